// Round 1
// baseline (1514.019 us; speedup 1.0000x reference)
//
#include <hip/hip_runtime.h>
#include <stdint.h>

// GIN GNN: N=40000 nodes, E=640000 edges, H=128, 5 layers, PROJ=256.
// Pipeline per launch:
//   atom_encode -> edge counting-sort by dst (hist/scan/scatter, once) ->
//   5x [aggregate(+bondemb, fused z=(1+eps)h+agg) -> GEMM1(+BN stats) ->
//       BN1+relu+GEMM2(+BN stats) -> BN2 apply(+relu)] -> final projection GEMM.

__global__ __launch_bounds__(256) void atom_encode_k(
    const int* __restrict__ x, const float* __restrict__ aemb,
    float* __restrict__ h, int N)
{
  int idx = blockIdx.x * 256 + threadIdx.x;
  if (idx >= N * 64) return;
  int n = idx >> 6, lane = idx & 63;
  const int* xr = x + n * 9;
  float sx = 0.f, sy = 0.f;
#pragma unroll
  for (int f = 0; f < 9; ++f) {
    int v = xr[f];
    float2 e = ((const float2*)(aemb + (size_t)(f * 128 + v) * 128))[lane];
    sx += e.x; sy += e.y;
  }
  ((float2*)h)[idx] = make_float2(sx, sy);
}

__global__ void zero_int_k(int* p, int n) {
  int i = blockIdx.x * 256 + threadIdx.x;
  if (i < n) p[i] = 0;
}

__global__ void hist_k(const int* __restrict__ ei, int* __restrict__ cnt, int E) {
  int e = blockIdx.x * 256 + threadIdx.x;
  if (e >= E) return;
  atomicAdd(&cnt[ei[E + e]], 1);
}

// Single-block exclusive scan over cnt[0..N-1] -> row_start[0..N], copy to cursor.
__global__ __launch_bounds__(1024) void scan_k(
    const int* __restrict__ cnt, int* __restrict__ row_start,
    int* __restrict__ cursor, int N)
{
  __shared__ int part[1024];
  int t = threadIdx.x;
  int CH = (N + 1023) / 1024;
  int base = t * CH;
  int s = 0;
  for (int i = 0; i < CH; ++i) {
    int idx = base + i;
    if (idx < N) s += cnt[idx];
  }
  part[t] = s;
  __syncthreads();
  for (int off = 1; off < 1024; off <<= 1) {
    int v = (t >= off) ? part[t - off] : 0;
    __syncthreads();
    part[t] += v;
    __syncthreads();
  }
  int run = (t == 0) ? 0 : part[t - 1];
  for (int i = 0; i < CH; ++i) {
    int idx = base + i;
    if (idx < N) {
      row_start[idx] = run;
      cursor[idx] = run;
      run += cnt[idx];
    }
  }
  if (t == 1023) row_start[N] = part[1023];
}

// Pack src (16b) + 3x4b bond attrs into one uint32, scatter to dst-sorted order.
__global__ void scatter_k(const int* __restrict__ ei, const int* __restrict__ ea,
                          int* __restrict__ cursor, uint32_t* __restrict__ sorted, int E)
{
  int e = blockIdx.x * 256 + threadIdx.x;
  if (e >= E) return;
  int src = ei[e], dst = ei[E + e];
  int a0 = ea[e * 3], a1 = ea[e * 3 + 1], a2 = ea[e * 3 + 2];
  int pos = atomicAdd(&cursor[dst], 1);
  sorted[pos] = (uint32_t)src | ((uint32_t)a0 << 16) | ((uint32_t)a1 << 20) | ((uint32_t)a2 << 24);
}

// One wave per node: gather h[src]+bond_emb, relu, sum; z = (1+eps)*h + agg.
// Also zeroes stats[0..511] (BN1 sums) from block 0 for the following GEMM.
__global__ __launch_bounds__(256) void aggregate_k(
    const float* __restrict__ h, const float* __restrict__ bemb,
    const uint32_t* __restrict__ sorted, const int* __restrict__ rs,
    const float* __restrict__ eps, int layer, float* __restrict__ z,
    float* __restrict__ stats, int N)
{
  if (blockIdx.x == 0) {
    stats[threadIdx.x] = 0.f;
    stats[threadIdx.x + 256] = 0.f;
  }
  int wave = threadIdx.x >> 6, lane = threadIdx.x & 63;
  int n = blockIdx.x * 4 + wave;
  if (n >= N) return;
  int beg = rs[n], end = rs[n + 1];
  const float2* bond = (const float2*)bemb;  // [3][16][64] as float2
  const float2* h2 = (const float2*)h;
  float ax = 0.f, ay = 0.f;
  for (int i = beg; i < end; ++i) {
    uint32_t p = sorted[i];
    int src = p & 0xFFFFu;
    int a0 = (p >> 16) & 15, a1 = (p >> 20) & 15, a2 = (p >> 24) & 15;
    float2 e0 = bond[a0 * 64 + lane];
    float2 e1 = bond[(16 + a1) * 64 + lane];
    float2 e2 = bond[(32 + a2) * 64 + lane];
    float2 hv = h2[src * 64 + lane];
    ax += fmaxf(hv.x + e0.x + e1.x + e2.x, 0.f);
    ay += fmaxf(hv.y + e0.y + e1.y + e2.y, 0.f);
  }
  float s = 1.f + eps[layer];
  float2 hn = h2[n * 64 + lane];
  ((float2*)z)[n * 64 + lane] = make_float2(fmaf(s, hn.x, ax), fmaf(s, hn.y, ay));
}

// GEMM [N,128] @ [128,256] + bias -> out [N,256]; optional per-column
// sum/sumsq stats (atomic, block-reduced); optional zeroing of next stats region.
__global__ __launch_bounds__(256) void gemm_k128n256_k(
    const float* __restrict__ in, const float* __restrict__ w,
    const float* __restrict__ bias, float* __restrict__ out,
    float* __restrict__ statsOut, float* __restrict__ zeroPtr, int zeroN)
{
  __shared__ float lds[4 * 16 * 128];  // 32 KB: 4 waves x 16 rows x 128
  int wave = threadIdx.x >> 6, lane = threadIdx.x & 63;
  int row0 = blockIdx.x * 64 + wave * 16;
  if (zeroPtr && blockIdx.x == 0 && threadIdx.x < zeroN) zeroPtr[threadIdx.x] = 0.f;
  float4* lf = (float4*)(lds + wave * 16 * 128);
  const float4* src = (const float4*)(in + (size_t)row0 * 128);
#pragma unroll
  for (int i = 0; i < 8; ++i) lf[lane + 64 * i] = src[lane + 64 * i];
  __syncthreads();
  float acc[16][4];
#pragma unroll
  for (int r = 0; r < 16; ++r) acc[r][0] = acc[r][1] = acc[r][2] = acc[r][3] = 0.f;
  for (int kk = 0; kk < 32; ++kk) {
    float4 w0 = ((const float4*)(w + (size_t)(4 * kk + 0) * 256))[lane];
    float4 w1v = ((const float4*)(w + (size_t)(4 * kk + 1) * 256))[lane];
    float4 w2v = ((const float4*)(w + (size_t)(4 * kk + 2) * 256))[lane];
    float4 w3v = ((const float4*)(w + (size_t)(4 * kk + 3) * 256))[lane];
#pragma unroll
    for (int r = 0; r < 16; ++r) {
      float4 zv = lf[r * 32 + kk];
      acc[r][0] += zv.x * w0.x + zv.y * w1v.x + zv.z * w2v.x + zv.w * w3v.x;
      acc[r][1] += zv.x * w0.y + zv.y * w1v.y + zv.z * w2v.y + zv.w * w3v.y;
      acc[r][2] += zv.x * w0.z + zv.y * w1v.z + zv.z * w2v.z + zv.w * w3v.z;
      acc[r][3] += zv.x * w0.w + zv.y * w1v.w + zv.z * w2v.w + zv.w * w3v.w;
    }
  }
  float4 bv = ((const float4*)bias)[lane];
  float s0 = 0, s1 = 0, s2 = 0, s3 = 0, q0 = 0, q1 = 0, q2 = 0, q3 = 0;
#pragma unroll
  for (int r = 0; r < 16; ++r) {
    float4 o = make_float4(acc[r][0] + bv.x, acc[r][1] + bv.y,
                           acc[r][2] + bv.z, acc[r][3] + bv.w);
    ((float4*)(out + (size_t)(row0 + r) * 256))[lane] = o;
    s0 += o.x; s1 += o.y; s2 += o.z; s3 += o.w;
    q0 += o.x * o.x; q1 += o.y * o.y; q2 += o.z * o.z; q3 += o.w * o.w;
  }
  if (statsOut) {
    __syncthreads();
    float* red = lds;
    int c = 4 * lane;
    red[wave * 256 + c + 0] = s0; red[wave * 256 + c + 1] = s1;
    red[wave * 256 + c + 2] = s2; red[wave * 256 + c + 3] = s3;
    red[1024 + wave * 256 + c + 0] = q0; red[1024 + wave * 256 + c + 1] = q1;
    red[1024 + wave * 256 + c + 2] = q2; red[1024 + wave * 256 + c + 3] = q3;
    __syncthreads();
    if (threadIdx.x < 256) {
      int cc = threadIdx.x;
      float ts = red[cc] + red[256 + cc] + red[512 + cc] + red[768 + cc];
      float tq = red[1024 + cc] + red[1280 + cc] + red[1536 + cc] + red[1792 + cc];
      atomicAdd(&statsOut[cc], ts);
      atomicAdd(&statsOut[256 + cc], tq);
    }
  }
}

// BN1(stats1)+relu applied at load, then [N,256] @ [256,128] + bias -> out [N,128];
// accumulates stats for BN2 into statsOut[0..255].
__global__ __launch_bounds__(256) void gemm_k256n128_k(
    const float* __restrict__ in, const float* __restrict__ w,
    const float* __restrict__ bias, const float* __restrict__ stats1,
    const float* __restrict__ g, const float* __restrict__ bb,
    float* __restrict__ out, float* __restrict__ statsOut, float invN)
{
  __shared__ float lds[4 * 16 * 256];  // 64 KB
  __shared__ float sscale[256], sshift[256];
  int wave = threadIdx.x >> 6, lane = threadIdx.x & 63;
  int row0 = blockIdx.x * 64 + wave * 16;
  {
    int c = threadIdx.x;
    float mu = stats1[c] * invN;
    float var = stats1[256 + c] * invN - mu * mu;
    float rsg = rsqrtf(var + 1e-5f) * g[c];
    sscale[c] = rsg;
    sshift[c] = bb[c] - mu * rsg;
  }
  __syncthreads();
  float4* lf = (float4*)(lds + wave * 16 * 256);
  const float4* src = (const float4*)(in + (size_t)row0 * 256);
  const float4* sc4 = (const float4*)sscale;
  const float4* sh4 = (const float4*)sshift;
#pragma unroll
  for (int i = 0; i < 16; ++i) {
    int idx = lane + 64 * i;
    float4 v = src[idx];
    int c4 = idx & 63;
    float4 scv = sc4[c4], shv = sh4[c4];
    v.x = fmaxf(fmaf(v.x, scv.x, shv.x), 0.f);
    v.y = fmaxf(fmaf(v.y, scv.y, shv.y), 0.f);
    v.z = fmaxf(fmaf(v.z, scv.z, shv.z), 0.f);
    v.w = fmaxf(fmaf(v.w, scv.w, shv.w), 0.f);
    lf[idx] = v;
  }
  __syncthreads();
  float acc[16][2];
#pragma unroll
  for (int r = 0; r < 16; ++r) acc[r][0] = acc[r][1] = 0.f;
  for (int kk = 0; kk < 64; ++kk) {
    float2 w0 = ((const float2*)(w + (size_t)(4 * kk + 0) * 128))[lane];
    float2 w1v = ((const float2*)(w + (size_t)(4 * kk + 1) * 128))[lane];
    float2 w2v = ((const float2*)(w + (size_t)(4 * kk + 2) * 128))[lane];
    float2 w3v = ((const float2*)(w + (size_t)(4 * kk + 3) * 128))[lane];
#pragma unroll
    for (int r = 0; r < 16; ++r) {
      float4 zv = lf[r * 64 + kk];
      acc[r][0] += zv.x * w0.x + zv.y * w1v.x + zv.z * w2v.x + zv.w * w3v.x;
      acc[r][1] += zv.x * w0.y + zv.y * w1v.y + zv.z * w2v.y + zv.w * w3v.y;
    }
  }
  float2 bv = ((const float2*)bias)[lane];
  float s0 = 0, s1 = 0, q0 = 0, q1 = 0;
#pragma unroll
  for (int r = 0; r < 16; ++r) {
    float2 o = make_float2(acc[r][0] + bv.x, acc[r][1] + bv.y);
    ((float2*)(out + (size_t)(row0 + r) * 128))[lane] = o;
    s0 += o.x; s1 += o.y;
    q0 += o.x * o.x; q1 += o.y * o.y;
  }
  __syncthreads();
  float* red = lds;
  int c = 2 * lane;
  red[wave * 128 + c] = s0; red[wave * 128 + c + 1] = s1;
  red[512 + wave * 128 + c] = q0; red[512 + wave * 128 + c + 1] = q1;
  __syncthreads();
  if (threadIdx.x < 128) {
    int cc = threadIdx.x;
    float ts = red[cc] + red[128 + cc] + red[256 + cc] + red[384 + cc];
    float tq = red[512 + cc] + red[640 + cc] + red[768 + cc] + red[896 + cc];
    atomicAdd(&statsOut[cc], ts);
    atomicAdd(&statsOut[128 + cc], tq);
  }
}

// h = BN2(z2) (+relu unless last layer)
__global__ __launch_bounds__(256) void bn_apply_k(
    const float* __restrict__ z2, const float* __restrict__ stats2,
    const float* __restrict__ g, const float* __restrict__ bb,
    float* __restrict__ h, float invN, int do_relu, int N)
{
  __shared__ float sscale[128], sshift[128];
  if (threadIdx.x < 128) {
    int c = threadIdx.x;
    float mu = stats2[c] * invN;
    float var = stats2[128 + c] * invN - mu * mu;
    float rsg = rsqrtf(var + 1e-5f) * g[c];
    sscale[c] = rsg;
    sshift[c] = bb[c] - mu * rsg;
  }
  __syncthreads();
  int idx = blockIdx.x * 256 + threadIdx.x;  // float4 index over N*32
  if (idx >= N * 32) return;
  int c4 = idx & 31;
  float4 v = ((const float4*)z2)[idx];
  float4 scv = ((const float4*)sscale)[c4], shv = ((const float4*)sshift)[c4];
  v.x = fmaf(v.x, scv.x, shv.x);
  v.y = fmaf(v.y, scv.y, shv.y);
  v.z = fmaf(v.z, scv.z, shv.z);
  v.w = fmaf(v.w, scv.w, shv.w);
  if (do_relu) {
    v.x = fmaxf(v.x, 0.f); v.y = fmaxf(v.y, 0.f);
    v.z = fmaxf(v.z, 0.f); v.w = fmaxf(v.w, 0.f);
  }
  ((float4*)h)[idx] = v;
}

extern "C" void kernel_launch(void* const* d_in, const int* in_sizes, int n_in,
                              void* d_out, int out_size, void* d_ws, size_t ws_size,
                              hipStream_t stream)
{
  const int* x = (const int*)d_in[0];
  const int* ei = (const int*)d_in[1];
  const int* ea = (const int*)d_in[2];
  const float* aemb = (const float*)d_in[3];
  const float* bemb = (const float*)d_in[4];
  const float* eps = (const float*)d_in[5];
  const float* w1 = (const float*)d_in[6];
  const float* b1 = (const float*)d_in[7];
  const float* bn1g = (const float*)d_in[8];
  const float* bn1b = (const float*)d_in[9];
  const float* w2 = (const float*)d_in[10];
  const float* b2 = (const float*)d_in[11];
  const float* bng = (const float*)d_in[12];
  const float* bnb = (const float*)d_in[13];
  const float* linw = (const float*)d_in[14];
  const float* linb = (const float*)d_in[15];
  int N = in_sizes[0] / 9;   // 40000
  int E = in_sizes[1] / 2;   // 640000

  char* ws = (char*)d_ws;
  size_t off = 0;
  auto alloc = [&](size_t bytes) {
    void* p = ws + off;
    off += (bytes + 255) & ~(size_t)255;
    return p;
  };
  float* h = (float*)alloc((size_t)N * 128 * 4);
  float* z = (float*)alloc((size_t)N * 128 * 4);   // z pre-GEMM1; reused for z2
  float* z1 = (float*)alloc((size_t)N * 256 * 4);
  uint32_t* sorted = (uint32_t*)alloc((size_t)E * 4);
  int* rs = (int*)alloc((size_t)(N + 1) * 4);
  int* cursor = (int*)alloc((size_t)N * 4);
  int* cnt = (int*)alloc((size_t)N * 4);
  float* stats = (float*)alloc(768 * 4);  // [sum1:256][sq1:256][sum2:128][sq2:128]
  float invN = 1.f / (float)N;

  atom_encode_k<<<(N * 64 + 255) / 256, 256, 0, stream>>>(x, aemb, h, N);
  zero_int_k<<<(N + 255) / 256, 256, 0, stream>>>(cnt, N);
  hist_k<<<(E + 255) / 256, 256, 0, stream>>>(ei, cnt, E);
  scan_k<<<1, 1024, 0, stream>>>(cnt, rs, cursor, N);
  scatter_k<<<(E + 255) / 256, 256, 0, stream>>>(ei, ea, cursor, sorted, E);

  for (int l = 0; l < 5; ++l) {
    aggregate_k<<<(N + 3) / 4, 256, 0, stream>>>(
        h, bemb + (size_t)l * 3 * 16 * 128, sorted, rs, eps, l, z, stats, N);
    gemm_k128n256_k<<<N / 64, 256, 0, stream>>>(
        z, w1 + (size_t)l * 128 * 256, b1 + (size_t)l * 256, z1,
        stats, stats + 512, 256);
    gemm_k256n128_k<<<N / 64, 256, 0, stream>>>(
        z1, w2 + (size_t)l * 256 * 128, b2 + (size_t)l * 128,
        stats, bn1g + (size_t)l * 256, bn1b + (size_t)l * 256,
        z, stats + 512, invN);
    bn_apply_k<<<(N * 32 + 255) / 256, 256, 0, stream>>>(
        z, stats + 512, bng + (size_t)l * 128, bnb + (size_t)l * 128,
        h, invN, (l < 4) ? 1 : 0, N);
  }
  gemm_k128n256_k<<<N / 64, 256, 0, stream>>>(
      h, linw, linb, (float*)d_out, nullptr, nullptr, 0);
}

// Round 2
// 1344.964 us; speedup vs baseline: 1.1257x; 1.1257x over previous
//
#include <hip/hip_runtime.h>
#include <stdint.h>

// GIN GNN: N=40000, E=640000, H=128, 5 layers, PROJ=256.
// R2: multi-block scan (was 101us single-block), BN2 fused into next
// aggregate / final GEMM (bn_apply_k deleted), combined bond table
// (1 gather/edge instead of 3).

__global__ __launch_bounds__(256) void atom_encode_k(
    const int* __restrict__ x, const float* __restrict__ aemb,
    float* __restrict__ h, int N)
{
  int idx = blockIdx.x * 256 + threadIdx.x;
  if (idx >= N * 64) return;
  int n = idx >> 6, lane = idx & 63;
  const int* xr = x + n * 9;
  float sx = 0.f, sy = 0.f;
#pragma unroll
  for (int f = 0; f < 9; ++f) {
    int v = xr[f];
    float2 e = ((const float2*)(aemb + (size_t)(f * 128 + v) * 128))[lane];
    sx += e.x; sy += e.y;
  }
  ((float2*)h)[idx] = make_float2(sx, sy);
}

// Precompute combined bond embedding: comb[l][c][128], c = a0|a1<<4|a2<<8.
__global__ __launch_bounds__(256) void bond_comb_k(
    const float* __restrict__ bemb, float* __restrict__ comb)
{
  int idx = blockIdx.x * 256 + threadIdx.x;  // over 5*4096*64 float2 slots
  int lane = idx & 63;
  int c = (idx >> 6) & 4095;
  int l = idx >> 18;
  if (l >= 5) return;
  int a0 = c & 15, a1 = (c >> 4) & 15, a2 = (c >> 8) & 15;
  const float2* b2 = (const float2*)(bemb + (size_t)l * 3 * 16 * 128);
  float2 e0 = b2[a0 * 64 + lane];
  float2 e1 = b2[(16 + a1) * 64 + lane];
  float2 e2 = b2[(32 + a2) * 64 + lane];
  ((float2*)comb)[idx] = make_float2(e0.x + e1.x + e2.x, e0.y + e1.y + e2.y);
}

__global__ void zero_int_k(int* p, int n) {
  int i = blockIdx.x * 256 + threadIdx.x;
  if (i < n) p[i] = 0;
}

__global__ void hist_k(const int* __restrict__ ei, int* __restrict__ cnt, int E) {
  int e = blockIdx.x * 256 + threadIdx.x;
  if (e >= E) return;
  atomicAdd(&cnt[ei[E + e]], 1);
}

// --- multi-block exclusive scan of cnt[0..N-1] ---
__global__ __launch_bounds__(256) void block_sum_k(
    const int* __restrict__ cnt, int* __restrict__ bsum, int N)
{
  __shared__ int red[256];
  int t = threadIdx.x, idx = blockIdx.x * 256 + t;
  red[t] = (idx < N) ? cnt[idx] : 0;
  __syncthreads();
  for (int o = 128; o > 0; o >>= 1) {
    if (t < o) red[t] += red[t + o];
    __syncthreads();
  }
  if (t == 0) bsum[blockIdx.x] = red[0];
}

__global__ __launch_bounds__(256) void scan_bsum_k(
    int* __restrict__ bsum, int* __restrict__ rsN, int nb)
{
  __shared__ int s[256];
  int t = threadIdx.x;
  s[t] = (t < nb) ? bsum[t] : 0;
  __syncthreads();
  for (int o = 1; o < 256; o <<= 1) {
    int v = (t >= o) ? s[t - o] : 0;
    __syncthreads();
    s[t] += v;
    __syncthreads();
  }
  if (t < nb) bsum[t] = (t == 0) ? 0 : s[t - 1];
  if (t == nb - 1) *rsN = s[t];
}

__global__ __launch_bounds__(256) void scan_write_k(
    const int* __restrict__ cnt, const int* __restrict__ bsum,
    int* __restrict__ rs, int* __restrict__ cursor, int N)
{
  __shared__ int s[256];
  int t = threadIdx.x, idx = blockIdx.x * 256 + t;
  int v = (idx < N) ? cnt[idx] : 0;
  s[t] = v;
  __syncthreads();
  for (int o = 1; o < 256; o <<= 1) {
    int u = (t >= o) ? s[t - o] : 0;
    __syncthreads();
    s[t] += u;
    __syncthreads();
  }
  int excl = s[t] - v + bsum[blockIdx.x];
  if (idx < N) { rs[idx] = excl; cursor[idx] = excl; }
}

// Pack src(16b) + combined bond idx(12b) into uint32, scatter dst-sorted.
__global__ void scatter_k(const int* __restrict__ ei, const int* __restrict__ ea,
                          int* __restrict__ cursor, uint32_t* __restrict__ sorted, int E)
{
  int e = blockIdx.x * 256 + threadIdx.x;
  if (e >= E) return;
  int src = ei[e], dst = ei[E + e];
  int a0 = ea[e * 3], a1 = ea[e * 3 + 1], a2 = ea[e * 3 + 2];
  int pos = atomicAdd(&cursor[dst], 1);
  sorted[pos] = (uint32_t)src | ((uint32_t)a0 << 16) | ((uint32_t)a1 << 20) | ((uint32_t)a2 << 24);
}

// One wave per node. Input hraw is PRE-BN (except layer 0: identity);
// BN2(+relu) of the previous layer applied on the fly via per-lane sc/sh.
// z = (1+eps)*hbn + sum_e relu(hbn[src] + comb[c]).
// Block 0 zeroes stats[0..511] (BN1 accumulators for the next GEMM).
__global__ __launch_bounds__(256) void aggregate_k(
    const float* __restrict__ hraw, const float* __restrict__ comb,
    const uint32_t* __restrict__ sorted, const int* __restrict__ rs,
    const float* __restrict__ eps, int layer, float* __restrict__ z,
    float* __restrict__ stats, const float* __restrict__ stats2,
    const float* __restrict__ g, const float* __restrict__ bb,
    float invN, int N)
{
  if (blockIdx.x == 0) {
    stats[threadIdx.x] = 0.f;
    stats[threadIdx.x + 256] = 0.f;
  }
  int wave = threadIdx.x >> 6, lane = threadIdx.x & 63;
  int n = blockIdx.x * 4 + wave;
  if (n >= N) return;
  float scx = 1.f, scy = 1.f, shx = 0.f, shy = 0.f;
  const bool bn = (stats2 != nullptr);
  if (bn) {
    int c0 = 2 * lane, c1 = c0 + 1;
    float mu0 = stats2[c0] * invN, mu1 = stats2[c1] * invN;
    float v0 = stats2[128 + c0] * invN - mu0 * mu0;
    float v1 = stats2[128 + c1] * invN - mu1 * mu1;
    scx = rsqrtf(v0 + 1e-5f) * g[c0];
    scy = rsqrtf(v1 + 1e-5f) * g[c1];
    shx = bb[c0] - mu0 * scx;
    shy = bb[c1] - mu1 * scy;
  }
  int beg = rs[n], end = rs[n + 1];
  const float2* h2 = (const float2*)hraw;
  const float2* cb = ((const float2*)comb) + (size_t)layer * 4096 * 64;
  float ax = 0.f, ay = 0.f;
  for (int i = beg; i < end; ++i) {
    uint32_t p = sorted[i];
    int src = p & 0xFFFFu;
    int c = p >> 16;
    float2 e = cb[c * 64 + lane];
    float2 hv = h2[src * 64 + lane];
    if (bn) {
      hv.x = fmaxf(fmaf(hv.x, scx, shx), 0.f);
      hv.y = fmaxf(fmaf(hv.y, scy, shy), 0.f);
    }
    ax += fmaxf(hv.x + e.x, 0.f);
    ay += fmaxf(hv.y + e.y, 0.f);
  }
  float s = 1.f + eps[layer];
  float2 hn = h2[n * 64 + lane];
  if (bn) {
    hn.x = fmaxf(fmaf(hn.x, scx, shx), 0.f);
    hn.y = fmaxf(fmaf(hn.y, scy, shy), 0.f);
  }
  ((float2*)z)[n * 64 + lane] = make_float2(fmaf(s, hn.x, ax), fmaf(s, hn.y, ay));
}

// GEMM [N,128]@[128,256]+bias -> [N,256]. Optional BN-on-load (final
// projection: stats2/g/bb, NO relu). Optional per-column stats accum +
// zeroing of the next stats region.
__global__ __launch_bounds__(256) void gemm_k128n256_k(
    const float* __restrict__ in, const float* __restrict__ w,
    const float* __restrict__ bias, float* __restrict__ out,
    float* __restrict__ statsOut, float* __restrict__ zeroPtr, int zeroN,
    const float* __restrict__ stats2, const float* __restrict__ g,
    const float* __restrict__ bb, float invN)
{
  __shared__ float lds[4 * 16 * 128];  // 32 KB
  __shared__ float sc[128], sh[128];
  int wave = threadIdx.x >> 6, lane = threadIdx.x & 63;
  int row0 = blockIdx.x * 64 + wave * 16;
  if (zeroPtr && blockIdx.x == 0 && threadIdx.x < zeroN) zeroPtr[threadIdx.x] = 0.f;
  if (stats2) {
    if (threadIdx.x < 128) {
      int c = threadIdx.x;
      float mu = stats2[c] * invN;
      float var = stats2[128 + c] * invN - mu * mu;
      float r = rsqrtf(var + 1e-5f) * g[c];
      sc[c] = r;
      sh[c] = bb[c] - mu * r;
    }
    __syncthreads();
  }
  float4* lf = (float4*)(lds + wave * 16 * 128);
  const float4* src = (const float4*)(in + (size_t)row0 * 128);
  const float4* sc4 = (const float4*)sc;
  const float4* sh4 = (const float4*)sh;
#pragma unroll
  for (int i = 0; i < 8; ++i) {
    int idx = lane + 64 * i;
    float4 v = src[idx];
    if (stats2) {
      int c4 = idx & 31;
      float4 scv = sc4[c4], shv = sh4[c4];
      v.x = fmaf(v.x, scv.x, shv.x);
      v.y = fmaf(v.y, scv.y, shv.y);
      v.z = fmaf(v.z, scv.z, shv.z);
      v.w = fmaf(v.w, scv.w, shv.w);
    }
    lf[idx] = v;
  }
  __syncthreads();
  float acc[16][4];
#pragma unroll
  for (int r = 0; r < 16; ++r) acc[r][0] = acc[r][1] = acc[r][2] = acc[r][3] = 0.f;
  for (int kk = 0; kk < 32; ++kk) {
    float4 w0 = ((const float4*)(w + (size_t)(4 * kk + 0) * 256))[lane];
    float4 w1v = ((const float4*)(w + (size_t)(4 * kk + 1) * 256))[lane];
    float4 w2v = ((const float4*)(w + (size_t)(4 * kk + 2) * 256))[lane];
    float4 w3v = ((const float4*)(w + (size_t)(4 * kk + 3) * 256))[lane];
#pragma unroll
    for (int r = 0; r < 16; ++r) {
      float4 zv = lf[r * 32 + kk];
      acc[r][0] += zv.x * w0.x + zv.y * w1v.x + zv.z * w2v.x + zv.w * w3v.x;
      acc[r][1] += zv.x * w0.y + zv.y * w1v.y + zv.z * w2v.y + zv.w * w3v.y;
      acc[r][2] += zv.x * w0.z + zv.y * w1v.z + zv.z * w2v.z + zv.w * w3v.z;
      acc[r][3] += zv.x * w0.w + zv.y * w1v.w + zv.z * w2v.w + zv.w * w3v.w;
    }
  }
  float4 bv = ((const float4*)bias)[lane];
  float s0 = 0, s1 = 0, s2 = 0, s3 = 0, q0 = 0, q1 = 0, q2 = 0, q3 = 0;
#pragma unroll
  for (int r = 0; r < 16; ++r) {
    float4 o = make_float4(acc[r][0] + bv.x, acc[r][1] + bv.y,
                           acc[r][2] + bv.z, acc[r][3] + bv.w);
    ((float4*)(out + (size_t)(row0 + r) * 256))[lane] = o;
    s0 += o.x; s1 += o.y; s2 += o.z; s3 += o.w;
    q0 += o.x * o.x; q1 += o.y * o.y; q2 += o.z * o.z; q3 += o.w * o.w;
  }
  if (statsOut) {
    __syncthreads();
    float* red = lds;
    int c = 4 * lane;
    red[wave * 256 + c + 0] = s0; red[wave * 256 + c + 1] = s1;
    red[wave * 256 + c + 2] = s2; red[wave * 256 + c + 3] = s3;
    red[1024 + wave * 256 + c + 0] = q0; red[1024 + wave * 256 + c + 1] = q1;
    red[1024 + wave * 256 + c + 2] = q2; red[1024 + wave * 256 + c + 3] = q3;
    __syncthreads();
    if (threadIdx.x < 256) {
      int cc = threadIdx.x;
      float ts = red[cc] + red[256 + cc] + red[512 + cc] + red[768 + cc];
      float tq = red[1024 + cc] + red[1280 + cc] + red[1536 + cc] + red[1792 + cc];
      atomicAdd(&statsOut[cc], ts);
      atomicAdd(&statsOut[256 + cc], tq);
    }
  }
}

// BN1(stats1)+relu at load, [N,256]@[256,128]+bias -> [N,128]; accumulates
// BN2 stats into statsOut[0..255].
__global__ __launch_bounds__(256) void gemm_k256n128_k(
    const float* __restrict__ in, const float* __restrict__ w,
    const float* __restrict__ bias, const float* __restrict__ stats1,
    const float* __restrict__ g, const float* __restrict__ bb,
    float* __restrict__ out, float* __restrict__ statsOut, float invN)
{
  __shared__ float lds[4 * 16 * 256];  // 64 KB
  __shared__ float sscale[256], sshift[256];
  int wave = threadIdx.x >> 6, lane = threadIdx.x & 63;
  int row0 = blockIdx.x * 64 + wave * 16;
  {
    int c = threadIdx.x;
    float mu = stats1[c] * invN;
    float var = stats1[256 + c] * invN - mu * mu;
    float rsg = rsqrtf(var + 1e-5f) * g[c];
    sscale[c] = rsg;
    sshift[c] = bb[c] - mu * rsg;
  }
  __syncthreads();
  float4* lf = (float4*)(lds + wave * 16 * 256);
  const float4* src = (const float4*)(in + (size_t)row0 * 256);
  const float4* sc4 = (const float4*)sscale;
  const float4* sh4 = (const float4*)sshift;
#pragma unroll
  for (int i = 0; i < 16; ++i) {
    int idx = lane + 64 * i;
    float4 v = src[idx];
    int c4 = idx & 63;
    float4 scv = sc4[c4], shv = sh4[c4];
    v.x = fmaxf(fmaf(v.x, scv.x, shv.x), 0.f);
    v.y = fmaxf(fmaf(v.y, scv.y, shv.y), 0.f);
    v.z = fmaxf(fmaf(v.z, scv.z, shv.z), 0.f);
    v.w = fmaxf(fmaf(v.w, scv.w, shv.w), 0.f);
    lf[idx] = v;
  }
  __syncthreads();
  float acc[16][2];
#pragma unroll
  for (int r = 0; r < 16; ++r) acc[r][0] = acc[r][1] = 0.f;
  for (int kk = 0; kk < 64; ++kk) {
    float2 w0 = ((const float2*)(w + (size_t)(4 * kk + 0) * 128))[lane];
    float2 w1v = ((const float2*)(w + (size_t)(4 * kk + 1) * 128))[lane];
    float2 w2v = ((const float2*)(w + (size_t)(4 * kk + 2) * 128))[lane];
    float2 w3v = ((const float2*)(w + (size_t)(4 * kk + 3) * 128))[lane];
#pragma unroll
    for (int r = 0; r < 16; ++r) {
      float4 zv = lf[r * 64 + kk];
      acc[r][0] += zv.x * w0.x + zv.y * w1v.x + zv.z * w2v.x + zv.w * w3v.x;
      acc[r][1] += zv.x * w0.y + zv.y * w1v.y + zv.z * w2v.y + zv.w * w3v.y;
    }
  }
  float2 bv = ((const float2*)bias)[lane];
  float s0 = 0, s1 = 0, q0 = 0, q1 = 0;
#pragma unroll
  for (int r = 0; r < 16; ++r) {
    float2 o = make_float2(acc[r][0] + bv.x, acc[r][1] + bv.y);
    ((float2*)(out + (size_t)(row0 + r) * 128))[lane] = o;
    s0 += o.x; s1 += o.y;
    q0 += o.x * o.x; q1 += o.y * o.y;
  }
  __syncthreads();
  float* red = lds;
  int c = 2 * lane;
  red[wave * 128 + c] = s0; red[wave * 128 + c + 1] = s1;
  red[512 + wave * 128 + c] = q0; red[512 + wave * 128 + c + 1] = q1;
  __syncthreads();
  if (threadIdx.x < 128) {
    int cc = threadIdx.x;
    float ts = red[cc] + red[128 + cc] + red[256 + cc] + red[384 + cc];
    float tq = red[512 + cc] + red[640 + cc] + red[768 + cc] + red[896 + cc];
    atomicAdd(&statsOut[cc], ts);
    atomicAdd(&statsOut[128 + cc], tq);
  }
}

extern "C" void kernel_launch(void* const* d_in, const int* in_sizes, int n_in,
                              void* d_out, int out_size, void* d_ws, size_t ws_size,
                              hipStream_t stream)
{
  const int* x = (const int*)d_in[0];
  const int* ei = (const int*)d_in[1];
  const int* ea = (const int*)d_in[2];
  const float* aemb = (const float*)d_in[3];
  const float* bemb = (const float*)d_in[4];
  const float* eps = (const float*)d_in[5];
  const float* w1 = (const float*)d_in[6];
  const float* b1 = (const float*)d_in[7];
  const float* bn1g = (const float*)d_in[8];
  const float* bn1b = (const float*)d_in[9];
  const float* w2 = (const float*)d_in[10];
  const float* b2 = (const float*)d_in[11];
  const float* bng = (const float*)d_in[12];
  const float* bnb = (const float*)d_in[13];
  const float* linw = (const float*)d_in[14];
  const float* linb = (const float*)d_in[15];
  int N = in_sizes[0] / 9;   // 40000
  int E = in_sizes[1] / 2;   // 640000
  int nb = (N + 255) / 256;  // 157

  char* ws = (char*)d_ws;
  size_t off = 0;
  auto alloc = [&](size_t bytes) {
    void* p = ws + off;
    off += (bytes + 255) & ~(size_t)255;
    return p;
  };
  float* raw = (float*)alloc((size_t)N * 128 * 4);  // pre-BN h (gemm2 out)
  float* zin = (float*)alloc((size_t)N * 128 * 4);  // aggregate out / gemm1 in
  float* z1  = (float*)alloc((size_t)N * 256 * 4);
  float* comb = (float*)alloc((size_t)5 * 4096 * 128 * 4);  // 10.5 MB
  uint32_t* sorted = (uint32_t*)alloc((size_t)E * 4);
  int* rs = (int*)alloc((size_t)(N + 1) * 4);
  int* cursor = (int*)alloc((size_t)N * 4);
  int* cnt = (int*)alloc((size_t)N * 4);
  int* bsum = (int*)alloc((size_t)nb * 4);
  float* stats = (float*)alloc(768 * 4);  // [sum1:256][sq1:256][sum2:128][sq2:128]
  float invN = 1.f / (float)N;

  atom_encode_k<<<(N * 64 + 255) / 256, 256, 0, stream>>>(x, aemb, raw, N);
  bond_comb_k<<<(5 * 4096 * 64 + 255) / 256, 256, 0, stream>>>(bemb, comb);
  zero_int_k<<<(N + 255) / 256, 256, 0, stream>>>(cnt, N);
  hist_k<<<(E + 255) / 256, 256, 0, stream>>>(ei, cnt, E);
  block_sum_k<<<nb, 256, 0, stream>>>(cnt, bsum, N);
  scan_bsum_k<<<1, 256, 0, stream>>>(bsum, rs + N, nb);
  scan_write_k<<<nb, 256, 0, stream>>>(cnt, bsum, rs, cursor, N);
  scatter_k<<<(E + 255) / 256, 256, 0, stream>>>(ei, ea, cursor, sorted, E);

  for (int l = 0; l < 5; ++l) {
    const float* st2 = (l == 0) ? nullptr : stats + 512;
    const float* gg  = (l == 0) ? nullptr : bng + (size_t)(l - 1) * 128;
    const float* bbb = (l == 0) ? nullptr : bnb + (size_t)(l - 1) * 128;
    aggregate_k<<<(N + 3) / 4, 256, 0, stream>>>(
        raw, comb, sorted, rs, eps, l, zin, stats, st2, gg, bbb, invN, N);
    gemm_k128n256_k<<<N / 64, 256, 0, stream>>>(
        zin, w1 + (size_t)l * 128 * 256, b1 + (size_t)l * 256, z1,
        stats, stats + 512, 256, nullptr, nullptr, nullptr, invN);
    gemm_k256n128_k<<<N / 64, 256, 0, stream>>>(
        z1, w2 + (size_t)l * 256 * 128, b2 + (size_t)l * 128,
        stats, bn1g + (size_t)l * 256, bn1b + (size_t)l * 256,
        raw, stats + 512, invN);
  }
  // Final projection with BN(layer4) fused on load (no relu).
  gemm_k128n256_k<<<N / 64, 256, 0, stream>>>(
      raw, linw, linb, (float*)d_out, nullptr, nullptr, 0,
      stats + 512, bng + (size_t)4 * 128, bnb + (size_t)4 * 128, invN);
}

// Round 4
// 879.376 us; speedup vs baseline: 1.7217x; 1.5295x over previous
//
#include <hip/hip_runtime.h>
#include <stdint.h>

// GIN GNN: N=40000, E=640000, H=128, 5 layers, PROJ=256.
// R4: bf16 MFMA GEMMs kept, but all PRE-BN activations (raw h, z1) stored
// fp32 — bf16 rounding only after BN/relu at LDS staging (BN amplifies
// pre-BN rounding by |x|/sigma; post-BN rounding is benign). zin (GEMM1
// input) stays bf16 = the unavoidable MFMA input rounding.

typedef unsigned short ushort_t;
typedef unsigned int uint_t;
typedef __attribute__((ext_vector_type(8))) short bf16x8;
typedef __attribute__((ext_vector_type(16))) float f32x16;

#define MFMA32(a, b, c) __builtin_amdgcn_mfma_f32_32x32x16_bf16(a, b, c, 0, 0, 0)

__device__ inline ushort_t f2bf(float f) {
  uint_t u = __builtin_bit_cast(uint_t, f);
  u += 0x7FFFu + ((u >> 16) & 1u);
  return (ushort_t)(u >> 16);
}
__device__ inline float bf2f(uint_t h) {  // low 16 bits
  uint_t u = (h & 0xFFFFu) << 16;
  return __builtin_bit_cast(float, u);
}
__device__ inline uint_t pack2(float a, float b) {
  return (uint_t)f2bf(a) | ((uint_t)f2bf(b) << 16);
}
__device__ inline f32x16 zero16() {
  f32x16 z;
#pragma unroll
  for (int i = 0; i < 16; ++i) z[i] = 0.f;
  return z;
}

// ---------- precompute ----------

// comb[l][c][128] bf16, c = a0|a1<<4|a2<<8
__global__ __launch_bounds__(256) void bond_comb_k(
    const float* __restrict__ bemb, ushort_t* __restrict__ comb)
{
  int idx = blockIdx.x * 256 + threadIdx.x;  // over 5*4096*64
  if (idx >= 5 * 4096 * 64) return;
  int lane = idx & 63, c = (idx >> 6) & 4095, l = idx >> 18;
  const float2* b2 = (const float2*)(bemb + (size_t)l * 3 * 16 * 128);
  float2 e0 = b2[(c & 15) * 64 + lane];
  float2 e1 = b2[(16 + ((c >> 4) & 15)) * 64 + lane];
  float2 e2 = b2[(32 + (c >> 8)) * 64 + lane];
  ((uint_t*)comb)[idx] = pack2(e0.x + e1.x + e2.x, e0.y + e1.y + e2.y);
}

// Swizzle [K=128][N=256] fp32 weight into B-frag order:
// o[((s*8+nt)*64+lane)*8 + j] = bf16(w[(s*16+(lane>>5)*8+j)*256 + nt*32+(lane&31)])
__global__ __launch_bounds__(256) void swz_w1_k(
    const float* __restrict__ w, ushort_t* __restrict__ o)
{
  int t = blockIdx.x * 256 + threadIdx.x;  // 8*8*64 = 4096
  if (t >= 4096) return;
  int lane = t & 63, nt = (t >> 6) & 7, s = t >> 9;
  int kb = s * 16 + (lane >> 5) * 8, n = nt * 32 + (lane & 31);
  ushort_t tmp[8];
#pragma unroll
  for (int j = 0; j < 8; ++j) tmp[j] = f2bf(w[(size_t)(kb + j) * 256 + n]);
  ((uint4*)o)[t] = *(uint4*)tmp;
}

// Swizzle [K=256][N=128]: o[((s*4+nt)*64+lane)*8 + j], s in [0,16), nt in [0,4)
__global__ __launch_bounds__(256) void swz_w2_k(
    const float* __restrict__ w, ushort_t* __restrict__ o)
{
  int t = blockIdx.x * 256 + threadIdx.x;  // 16*4*64 = 4096
  if (t >= 4096) return;
  int lane = t & 63, nt = (t >> 6) & 3, s = t >> 8;
  int kb = s * 16 + (lane >> 5) * 8, n = nt * 32 + (lane & 31);
  ushort_t tmp[8];
#pragma unroll
  for (int j = 0; j < 8; ++j) tmp[j] = f2bf(w[(size_t)(kb + j) * 128 + n]);
  ((uint4*)o)[t] = *(uint4*)tmp;
}

// ---------- graph preprocessing ----------

__global__ void zero_int_k(int* p, int n) {
  int i = blockIdx.x * 256 + threadIdx.x;
  if (i < n) p[i] = 0;
}

__global__ void hist_k(const int* __restrict__ ei, int* __restrict__ cnt, int E) {
  int e = blockIdx.x * 256 + threadIdx.x;
  if (e >= E) return;
  atomicAdd(&cnt[ei[E + e]], 1);
}

__global__ __launch_bounds__(256) void block_sum_k(
    const int* __restrict__ cnt, int* __restrict__ bsum, int N)
{
  __shared__ int red[256];
  int t = threadIdx.x, idx = blockIdx.x * 256 + t;
  red[t] = (idx < N) ? cnt[idx] : 0;
  __syncthreads();
  for (int o = 128; o > 0; o >>= 1) {
    if (t < o) red[t] += red[t + o];
    __syncthreads();
  }
  if (t == 0) bsum[blockIdx.x] = red[0];
}

__global__ __launch_bounds__(256) void scan_bsum_k(
    int* __restrict__ bsum, int* __restrict__ rsN, int nb)
{
  __shared__ int s[256];
  int t = threadIdx.x;
  s[t] = (t < nb) ? bsum[t] : 0;
  __syncthreads();
  for (int o = 1; o < 256; o <<= 1) {
    int v = (t >= o) ? s[t - o] : 0;
    __syncthreads();
    s[t] += v;
    __syncthreads();
  }
  if (t < nb) bsum[t] = (t == 0) ? 0 : s[t - 1];
  if (t == nb - 1) *rsN = s[t];
}

__global__ __launch_bounds__(256) void scan_write_k(
    const int* __restrict__ cnt, const int* __restrict__ bsum,
    int* __restrict__ rs, int* __restrict__ cursor, int N)
{
  __shared__ int s[256];
  int t = threadIdx.x, idx = blockIdx.x * 256 + t;
  int v = (idx < N) ? cnt[idx] : 0;
  s[t] = v;
  __syncthreads();
  for (int o = 1; o < 256; o <<= 1) {
    int u = (t >= o) ? s[t - o] : 0;
    __syncthreads();
    s[t] += u;
    __syncthreads();
  }
  int excl = s[t] - v + bsum[blockIdx.x];
  if (idx < N) { rs[idx] = excl; cursor[idx] = excl; }
}

__global__ void scatter_k(const int* __restrict__ ei, const int* __restrict__ ea,
                          int* __restrict__ cursor, uint32_t* __restrict__ sorted, int E)
{
  int e = blockIdx.x * 256 + threadIdx.x;
  if (e >= E) return;
  int src = ei[e], dst = ei[E + e];
  int a0 = ea[e * 3], a1 = ea[e * 3 + 1], a2 = ea[e * 3 + 2];
  int pos = atomicAdd(&cursor[dst], 1);
  sorted[pos] = (uint32_t)src | ((uint32_t)a0 << 16) | ((uint32_t)a1 << 20) | ((uint32_t)a2 << 24);
}

// ---------- node pipeline ----------

__global__ __launch_bounds__(256) void atom_encode_k(
    const int* __restrict__ x, const float* __restrict__ aemb,
    float* __restrict__ raw, int N)
{
  int idx = blockIdx.x * 256 + threadIdx.x;
  if (idx >= N * 64) return;
  int n = idx >> 6, lane = idx & 63;
  const int* xr = x + n * 9;
  float sx = 0.f, sy = 0.f;
#pragma unroll
  for (int f = 0; f < 9; ++f) {
    float2 e = ((const float2*)(aemb + (size_t)(f * 128 + xr[f]) * 128))[lane];
    sx += e.x; sy += e.y;
  }
  ((float2*)raw)[idx] = make_float2(sx, sy);
}

// One wave per node; applies previous layer's BN2(+relu) on the fly to fp32
// raw. zin(bf16) = (1+eps)*hbn + sum_e relu(hbn[src] + comb[c]).
// Block 0 zeroes stats[0..511] (BN1 accums).
__global__ __launch_bounds__(256) void aggregate_k(
    const float* __restrict__ raw, const ushort_t* __restrict__ comb,
    const uint32_t* __restrict__ sorted, const int* __restrict__ rs,
    const float* __restrict__ eps, int layer, ushort_t* __restrict__ zin,
    float* __restrict__ stats, const float* __restrict__ stats2,
    const float* __restrict__ g, const float* __restrict__ bb,
    float invN, int N)
{
  if (blockIdx.x == 0) {
    stats[threadIdx.x] = 0.f;
    stats[threadIdx.x + 256] = 0.f;
  }
  int wave = threadIdx.x >> 6, lane = threadIdx.x & 63;
  int n = blockIdx.x * 4 + wave;
  if (n >= N) return;
  float scx = 1.f, scy = 1.f, shx = 0.f, shy = 0.f;
  const bool bn = (stats2 != nullptr);
  if (bn) {
    int c0 = 2 * lane, c1 = c0 + 1;
    float mu0 = stats2[c0] * invN, mu1 = stats2[c1] * invN;
    float v0 = stats2[128 + c0] * invN - mu0 * mu0;
    float v1 = stats2[128 + c1] * invN - mu1 * mu1;
    scx = rsqrtf(v0 + 1e-5f) * g[c0];
    scy = rsqrtf(v1 + 1e-5f) * g[c1];
    shx = bb[c0] - mu0 * scx;
    shy = bb[c1] - mu1 * scy;
  }
  int beg = rs[n], end = rs[n + 1];
  const float2* h2 = (const float2*)raw;
  const uint_t* cb = ((const uint_t*)comb) + (size_t)layer * 4096 * 64;
  float ax = 0.f, ay = 0.f;
  for (int i = beg; i < end; ++i) {
    uint32_t p = sorted[i];
    int src = p & 0xFFFFu;
    int c = p >> 16;
    uint_t ee = cb[c * 64 + lane];
    float2 hv = h2[src * 64 + lane];
    if (bn) {
      hv.x = fmaxf(fmaf(hv.x, scx, shx), 0.f);
      hv.y = fmaxf(fmaf(hv.y, scy, shy), 0.f);
    }
    ax += fmaxf(hv.x + bf2f(ee), 0.f);
    ay += fmaxf(hv.y + bf2f(ee >> 16), 0.f);
  }
  float s = 1.f + eps[layer];
  float2 hn = h2[n * 64 + lane];
  if (bn) {
    hn.x = fmaxf(fmaf(hn.x, scx, shx), 0.f);
    hn.y = fmaxf(fmaf(hn.y, scy, shy), 0.f);
  }
  ((uint_t*)zin)[n * 64 + lane] = pack2(fmaf(s, hn.x, ax), fmaf(s, hn.y, ay));
}

// ---------- MFMA GEMMs ----------
// A staged in LDS, XOR-swizzled in 16B chunks: elem (r,k) at col
// ((k>>3)^(r&15))*8 + (k&7).   Frags: A[m=lane&31][k=(lane>>5)*8+j],
// B[k][n=lane&31][k=(lane>>5)*8+j] (pre-swizzled),
// C/D col=lane&31, row=(reg&3)+8*(reg>>2)+4*(lane>>5).

// [64,128]@[128,256]+bias -> fp32 out. Input either bf16 (inbf) or fp32
// (inf, with optional BN via stats2 — final projection). Optional BN1
// stats accum + zeroing of next stats region.
__global__ __launch_bounds__(256) void gemm1_k(
    const ushort_t* __restrict__ inbf, const float* __restrict__ inf,
    const ushort_t* __restrict__ bswz, const float* __restrict__ bias,
    float* __restrict__ outf, float* __restrict__ statsOut,
    float* __restrict__ zeroPtr, int zeroN,
    const float* __restrict__ stats2, const float* __restrict__ g,
    const float* __restrict__ bb, float invN)
{
  __shared__ ushort_t As[64 * 128];
  __shared__ float sc[128], sh[128];
  int tid = threadIdx.x;
  int wave = tid >> 6, lane = tid & 63;
  int lr = lane & 31, half = lane >> 5;
  int row0 = blockIdx.x * 64;
  if (zeroPtr && blockIdx.x == 0 && tid < zeroN) zeroPtr[tid] = 0.f;
  if (stats2 && tid < 128) {
    int c = tid;
    float mu = stats2[c] * invN;
    float var = stats2[128 + c] * invN - mu * mu;
    float r = rsqrtf(var + 1e-5f) * g[c];
    sc[c] = r;
    sh[c] = bb[c] - mu * r;
  }
  __syncthreads();
  if (inbf) {
    const uint2* src = (const uint2*)(inbf + (size_t)row0 * 128);
#pragma unroll
    for (int i = 0; i < 8; ++i) {
      int idx = tid + 256 * i;           // 2048 uint2 = 64x128
      int r = idx >> 5, c = (idx & 31) * 4;
      uint2 v = src[idx];
      int scol = (((c >> 3) ^ (r & 15)) << 3) | (c & 7);
      *(uint2*)&As[r * 128 + scol] = v;
    }
  } else {
    const float4* src = (const float4*)(inf + (size_t)row0 * 128);
#pragma unroll
    for (int i = 0; i < 8; ++i) {
      int idx = tid + 256 * i;           // 2048 float4 = 64x128
      int r = idx >> 5, c = (idx & 31) * 4;
      float4 v = src[idx];
      if (stats2) {
        v.x = fmaf(v.x, sc[c], sh[c]);
        v.y = fmaf(v.y, sc[c + 1], sh[c + 1]);
        v.z = fmaf(v.z, sc[c + 2], sh[c + 2]);
        v.w = fmaf(v.w, sc[c + 3], sh[c + 3]);
      }
      uint2 o;
      o.x = pack2(v.x, v.y);
      o.y = pack2(v.z, v.w);
      int scol = (((c >> 3) ^ (r & 15)) << 3) | (c & 7);
      *(uint2*)&As[r * 128 + scol] = o;
    }
  }
  __syncthreads();
  int nt0 = wave * 2, nt1 = nt0 + 1;
  f32x16 acc00 = zero16(), acc01 = zero16(), acc10 = zero16(), acc11 = zero16();
  const bf16x8* Bp = (const bf16x8*)bswz;
#pragma unroll
  for (int s = 0; s < 8; ++s) {
    int k = s * 16 + half * 8;
    int scol = ((k >> 3) ^ (lr & 15)) << 3;
    bf16x8 a0 = *(const bf16x8*)&As[lr * 128 + scol];
    bf16x8 a1 = *(const bf16x8*)&As[(32 + lr) * 128 + scol];
    bf16x8 b0 = Bp[(s * 8 + nt0) * 64 + lane];
    bf16x8 b1 = Bp[(s * 8 + nt1) * 64 + lane];
    acc00 = MFMA32(a0, b0, acc00);
    acc10 = MFMA32(a1, b0, acc10);
    acc01 = MFMA32(a0, b1, acc01);
    acc11 = MFMA32(a1, b1, acc11);
  }
  int col0 = nt0 * 32 + lr, col1 = nt1 * 32 + lr;
  float bv0 = bias[col0], bv1 = bias[col1];
  float s0 = 0, q0 = 0, s1 = 0, q1 = 0;
  auto emit = [&](const f32x16& a, int mtb, int col, float bv, float& s, float& q) {
#pragma unroll
    for (int r2 = 0; r2 < 16; ++r2) {
      int row = row0 + mtb + (r2 & 3) + 8 * (r2 >> 2) + 4 * half;
      float v = a[r2] + bv;
      outf[(size_t)row * 256 + col] = v;
      s += v;
      q += v * v;
    }
  };
  emit(acc00, 0, col0, bv0, s0, q0);
  emit(acc10, 32, col0, bv0, s0, q0);
  emit(acc01, 0, col1, bv1, s1, q1);
  emit(acc11, 32, col1, bv1, s1, q1);
  if (statsOut) {
    s0 += __shfl_xor(s0, 32);
    q0 += __shfl_xor(q0, 32);
    s1 += __shfl_xor(s1, 32);
    q1 += __shfl_xor(q1, 32);
    if (lane < 32) {
      atomicAdd(&statsOut[col0], s0);
      atomicAdd(&statsOut[256 + col0], q0);
      atomicAdd(&statsOut[col1], s1);
      atomicAdd(&statsOut[256 + col1], q1);
    }
  }
}

// BN1+relu on fp32 load -> bf16 LDS, [64,256]@[256,128]+bias -> raw fp32;
// BN2 stats out.
__global__ __launch_bounds__(256) void gemm2_k(
    const float* __restrict__ in, const ushort_t* __restrict__ bswz,
    const float* __restrict__ bias, const float* __restrict__ stats1,
    const float* __restrict__ g, const float* __restrict__ bb,
    float* __restrict__ outf, float* __restrict__ statsOut, float invN)
{
  __shared__ ushort_t As[64 * 256];
  __shared__ float sc[256], sh[256];
  int tid = threadIdx.x;
  int wave = tid >> 6, lane = tid & 63;
  int lr = lane & 31, half = lane >> 5;
  int row0 = blockIdx.x * 64;
  {
    int c = tid;
    float mu = stats1[c] * invN;
    float var = stats1[256 + c] * invN - mu * mu;
    float r = rsqrtf(var + 1e-5f) * g[c];
    sc[c] = r;
    sh[c] = bb[c] - mu * r;
  }
  __syncthreads();
  {
    const float4* src = (const float4*)(in + (size_t)row0 * 256);
#pragma unroll
    for (int i = 0; i < 16; ++i) {
      int idx = tid + 256 * i;           // 4096 float4 = 64x256
      int r = idx >> 6, c = (idx & 63) * 4;
      float4 v = src[idx];
      float f0 = fmaxf(fmaf(v.x, sc[c], sh[c]), 0.f);
      float f1 = fmaxf(fmaf(v.y, sc[c + 1], sh[c + 1]), 0.f);
      float f2 = fmaxf(fmaf(v.z, sc[c + 2], sh[c + 2]), 0.f);
      float f3 = fmaxf(fmaf(v.w, sc[c + 3], sh[c + 3]), 0.f);
      uint2 o;
      o.x = pack2(f0, f1);
      o.y = pack2(f2, f3);
      int scol = (((c >> 3) ^ (r & 15)) << 3) | (c & 7);
      *(uint2*)&As[r * 256 + scol] = o;
    }
  }
  __syncthreads();
  int nt = wave;
  f32x16 acc0 = zero16(), acc1 = zero16();
  const bf16x8* Bp = (const bf16x8*)bswz;
#pragma unroll
  for (int s = 0; s < 16; ++s) {
    int k = s * 16 + half * 8;
    int scol = ((k >> 3) ^ (lr & 15)) << 3;
    bf16x8 a0 = *(const bf16x8*)&As[lr * 256 + scol];
    bf16x8 a1 = *(const bf16x8*)&As[(32 + lr) * 256 + scol];
    bf16x8 b = Bp[(s * 4 + nt) * 64 + lane];
    acc0 = MFMA32(a0, b, acc0);
    acc1 = MFMA32(a1, b, acc1);
  }
  int col = nt * 32 + lr;
  float bv = bias[col];
  float s0 = 0, q0 = 0;
  auto emit = [&](const f32x16& a, int mtb) {
#pragma unroll
    for (int r2 = 0; r2 < 16; ++r2) {
      int row = row0 + mtb + (r2 & 3) + 8 * (r2 >> 2) + 4 * half;
      float v = a[r2] + bv;
      outf[(size_t)row * 128 + col] = v;
      s0 += v;
      q0 += v * v;
    }
  };
  emit(acc0, 0);
  emit(acc1, 32);
  s0 += __shfl_xor(s0, 32);
  q0 += __shfl_xor(q0, 32);
  if (lane < 32) {
    atomicAdd(&statsOut[col], s0);
    atomicAdd(&statsOut[128 + col], q0);
  }
}

extern "C" void kernel_launch(void* const* d_in, const int* in_sizes, int n_in,
                              void* d_out, int out_size, void* d_ws, size_t ws_size,
                              hipStream_t stream)
{
  const int* x = (const int*)d_in[0];
  const int* ei = (const int*)d_in[1];
  const int* ea = (const int*)d_in[2];
  const float* aemb = (const float*)d_in[3];
  const float* bemb = (const float*)d_in[4];
  const float* eps = (const float*)d_in[5];
  const float* w1 = (const float*)d_in[6];
  const float* b1 = (const float*)d_in[7];
  const float* bn1g = (const float*)d_in[8];
  const float* bn1b = (const float*)d_in[9];
  const float* w2 = (const float*)d_in[10];
  const float* b2 = (const float*)d_in[11];
  const float* bng = (const float*)d_in[12];
  const float* bnb = (const float*)d_in[13];
  const float* linw = (const float*)d_in[14];
  const float* linb = (const float*)d_in[15];
  int N = in_sizes[0] / 9;   // 40000
  int E = in_sizes[1] / 2;   // 640000
  int nb = (N + 255) / 256;

  char* ws = (char*)d_ws;
  size_t off = 0;
  auto alloc = [&](size_t bytes) {
    void* p = ws + off;
    off += (bytes + 255) & ~(size_t)255;
    return p;
  };
  float* raw = (float*)alloc((size_t)N * 128 * 4);         // pre-BN h, fp32
  float* z1  = (float*)alloc((size_t)N * 256 * 4);         // pre-BN1, fp32
  ushort_t* zin = (ushort_t*)alloc((size_t)N * 128 * 2);   // GEMM1 input, bf16
  ushort_t* comb = (ushort_t*)alloc((size_t)5 * 4096 * 128 * 2);
  ushort_t* bswz1 = (ushort_t*)alloc((size_t)6 * 32768 * 2);  // 5x w1 + linw
  ushort_t* bswz2 = (ushort_t*)alloc((size_t)5 * 32768 * 2);
  uint32_t* sorted = (uint32_t*)alloc((size_t)E * 4);
  int* rs = (int*)alloc((size_t)(N + 1) * 4);
  int* cursor = (int*)alloc((size_t)N * 4);
  int* cnt = (int*)alloc((size_t)N * 4);
  int* bsum = (int*)alloc((size_t)nb * 4);
  float* stats = (float*)alloc(768 * 4);
  float invN = 1.f / (float)N;

  bond_comb_k<<<(5 * 4096 * 64 + 255) / 256, 256, 0, stream>>>(bemb, comb);
  for (int l = 0; l < 5; ++l)
    swz_w1_k<<<16, 256, 0, stream>>>(w1 + (size_t)l * 32768, bswz1 + (size_t)l * 32768);
  swz_w1_k<<<16, 256, 0, stream>>>(linw, bswz1 + (size_t)5 * 32768);
  for (int l = 0; l < 5; ++l)
    swz_w2_k<<<16, 256, 0, stream>>>(w2 + (size_t)l * 32768, bswz2 + (size_t)l * 32768);

  atom_encode_k<<<(N * 64 + 255) / 256, 256, 0, stream>>>(x, aemb, raw, N);
  zero_int_k<<<(N + 255) / 256, 256, 0, stream>>>(cnt, N);
  hist_k<<<(E + 255) / 256, 256, 0, stream>>>(ei, cnt, E);
  block_sum_k<<<nb, 256, 0, stream>>>(cnt, bsum, N);
  scan_bsum_k<<<1, 256, 0, stream>>>(bsum, rs + N, nb);
  scan_write_k<<<nb, 256, 0, stream>>>(cnt, bsum, rs, cursor, N);
  scatter_k<<<(E + 255) / 256, 256, 0, stream>>>(ei, ea, cursor, sorted, E);

  for (int l = 0; l < 5; ++l) {
    const float* st2 = (l == 0) ? nullptr : stats + 512;
    const float* gg  = (l == 0) ? nullptr : bng + (size_t)(l - 1) * 128;
    const float* bbb = (l == 0) ? nullptr : bnb + (size_t)(l - 1) * 128;
    aggregate_k<<<(N + 3) / 4, 256, 0, stream>>>(
        raw, comb, sorted, rs, eps, l, zin, stats, st2, gg, bbb, invN, N);
    gemm1_k<<<N / 64, 256, 0, stream>>>(
        zin, nullptr, bswz1 + (size_t)l * 32768, b1 + (size_t)l * 256, z1,
        stats, stats + 512, 256, nullptr, nullptr, nullptr, invN);
    gemm2_k<<<N / 64, 256, 0, stream>>>(
        z1, bswz2 + (size_t)l * 32768, b2 + (size_t)l * 128,
        stats, bn1g + (size_t)l * 256, bn1b + (size_t)l * 256,
        raw, stats + 512, invN);
  }
  gemm1_k<<<N / 64, 256, 0, stream>>>(
      nullptr, raw, bswz1 + (size_t)5 * 32768, linb, (float*)d_out,
      nullptr, nullptr, 0, stats + 512, bng + (size_t)4 * 128, bnb + (size_t)4 * 128, invN);
}

// Round 5
// 750.670 us; speedup vs baseline: 2.0169x; 1.1715x over previous
//
#include <hip/hip_runtime.h>
#include <stdint.h>

// GIN GNN: N=40000, E=640000, H=128, 5 layers, PROJ=256.
// R5: aggregate_k edge loop software-pipelined (unroll 8, all gather loads
// issued before first use -> ~8x memory-level parallelism; was 1 edge in
// flight at 12 VGPRs, 83us/layer latency-bound).

typedef unsigned short ushort_t;
typedef unsigned int uint_t;
typedef __attribute__((ext_vector_type(8))) short bf16x8;
typedef __attribute__((ext_vector_type(16))) float f32x16;

#define MFMA32(a, b, c) __builtin_amdgcn_mfma_f32_32x32x16_bf16(a, b, c, 0, 0, 0)

__device__ inline ushort_t f2bf(float f) {
  uint_t u = __builtin_bit_cast(uint_t, f);
  u += 0x7FFFu + ((u >> 16) & 1u);
  return (ushort_t)(u >> 16);
}
__device__ inline float bf2f(uint_t h) {  // low 16 bits
  uint_t u = (h & 0xFFFFu) << 16;
  return __builtin_bit_cast(float, u);
}
__device__ inline uint_t pack2(float a, float b) {
  return (uint_t)f2bf(a) | ((uint_t)f2bf(b) << 16);
}
__device__ inline f32x16 zero16() {
  f32x16 z;
#pragma unroll
  for (int i = 0; i < 16; ++i) z[i] = 0.f;
  return z;
}

// ---------- precompute ----------

// comb[l][c][128] bf16, c = a0|a1<<4|a2<<8
__global__ __launch_bounds__(256) void bond_comb_k(
    const float* __restrict__ bemb, ushort_t* __restrict__ comb)
{
  int idx = blockIdx.x * 256 + threadIdx.x;  // over 5*4096*64
  if (idx >= 5 * 4096 * 64) return;
  int lane = idx & 63, c = (idx >> 6) & 4095, l = idx >> 18;
  const float2* b2 = (const float2*)(bemb + (size_t)l * 3 * 16 * 128);
  float2 e0 = b2[(c & 15) * 64 + lane];
  float2 e1 = b2[(16 + ((c >> 4) & 15)) * 64 + lane];
  float2 e2 = b2[(32 + (c >> 8)) * 64 + lane];
  ((uint_t*)comb)[idx] = pack2(e0.x + e1.x + e2.x, e0.y + e1.y + e2.y);
}

// Swizzle [K=128][N=256] fp32 weight into B-frag order:
// o[((s*8+nt)*64+lane)*8 + j] = bf16(w[(s*16+(lane>>5)*8+j)*256 + nt*32+(lane&31)])
__global__ __launch_bounds__(256) void swz_w1_k(
    const float* __restrict__ w, ushort_t* __restrict__ o)
{
  int t = blockIdx.x * 256 + threadIdx.x;  // 8*8*64 = 4096
  if (t >= 4096) return;
  int lane = t & 63, nt = (t >> 6) & 7, s = t >> 9;
  int kb = s * 16 + (lane >> 5) * 8, n = nt * 32 + (lane & 31);
  ushort_t tmp[8];
#pragma unroll
  for (int j = 0; j < 8; ++j) tmp[j] = f2bf(w[(size_t)(kb + j) * 256 + n]);
  ((uint4*)o)[t] = *(uint4*)tmp;
}

// Swizzle [K=256][N=128]: o[((s*4+nt)*64+lane)*8 + j], s in [0,16), nt in [0,4)
__global__ __launch_bounds__(256) void swz_w2_k(
    const float* __restrict__ w, ushort_t* __restrict__ o)
{
  int t = blockIdx.x * 256 + threadIdx.x;  // 16*4*64 = 4096
  if (t >= 4096) return;
  int lane = t & 63, nt = (t >> 6) & 3, s = t >> 8;
  int kb = s * 16 + (lane >> 5) * 8, n = nt * 32 + (lane & 31);
  ushort_t tmp[8];
#pragma unroll
  for (int j = 0; j < 8; ++j) tmp[j] = f2bf(w[(size_t)(kb + j) * 128 + n]);
  ((uint4*)o)[t] = *(uint4*)tmp;
}

// ---------- graph preprocessing ----------

__global__ void zero_int_k(int* p, int n) {
  int i = blockIdx.x * 256 + threadIdx.x;
  if (i < n) p[i] = 0;
}

__global__ void hist_k(const int* __restrict__ ei, int* __restrict__ cnt, int E) {
  int e = blockIdx.x * 256 + threadIdx.x;
  if (e >= E) return;
  atomicAdd(&cnt[ei[E + e]], 1);
}

__global__ __launch_bounds__(256) void block_sum_k(
    const int* __restrict__ cnt, int* __restrict__ bsum, int N)
{
  __shared__ int red[256];
  int t = threadIdx.x, idx = blockIdx.x * 256 + t;
  red[t] = (idx < N) ? cnt[idx] : 0;
  __syncthreads();
  for (int o = 128; o > 0; o >>= 1) {
    if (t < o) red[t] += red[t + o];
    __syncthreads();
  }
  if (t == 0) bsum[blockIdx.x] = red[0];
}

__global__ __launch_bounds__(256) void scan_bsum_k(
    int* __restrict__ bsum, int* __restrict__ rsN, int nb)
{
  __shared__ int s[256];
  int t = threadIdx.x;
  s[t] = (t < nb) ? bsum[t] : 0;
  __syncthreads();
  for (int o = 1; o < 256; o <<= 1) {
    int v = (t >= o) ? s[t - o] : 0;
    __syncthreads();
    s[t] += v;
    __syncthreads();
  }
  if (t < nb) bsum[t] = (t == 0) ? 0 : s[t - 1];
  if (t == nb - 1) *rsN = s[t];
}

__global__ __launch_bounds__(256) void scan_write_k(
    const int* __restrict__ cnt, const int* __restrict__ bsum,
    int* __restrict__ rs, int* __restrict__ cursor, int N)
{
  __shared__ int s[256];
  int t = threadIdx.x, idx = blockIdx.x * 256 + t;
  int v = (idx < N) ? cnt[idx] : 0;
  s[t] = v;
  __syncthreads();
  for (int o = 1; o < 256; o <<= 1) {
    int u = (t >= o) ? s[t - o] : 0;
    __syncthreads();
    s[t] += u;
    __syncthreads();
  }
  int excl = s[t] - v + bsum[blockIdx.x];
  if (idx < N) { rs[idx] = excl; cursor[idx] = excl; }
}

__global__ void scatter_k(const int* __restrict__ ei, const int* __restrict__ ea,
                          int* __restrict__ cursor, uint32_t* __restrict__ sorted, int E)
{
  int e = blockIdx.x * 256 + threadIdx.x;
  if (e >= E) return;
  int src = ei[e], dst = ei[E + e];
  int a0 = ea[e * 3], a1 = ea[e * 3 + 1], a2 = ea[e * 3 + 2];
  int pos = atomicAdd(&cursor[dst], 1);
  sorted[pos] = (uint32_t)src | ((uint32_t)a0 << 16) | ((uint32_t)a1 << 20) | ((uint32_t)a2 << 24);
}

// ---------- node pipeline ----------

__global__ __launch_bounds__(256) void atom_encode_k(
    const int* __restrict__ x, const float* __restrict__ aemb,
    float* __restrict__ raw, int N)
{
  int idx = blockIdx.x * 256 + threadIdx.x;
  if (idx >= N * 64) return;
  int n = idx >> 6, lane = idx & 63;
  const int* xr = x + n * 9;
  float sx = 0.f, sy = 0.f;
#pragma unroll
  for (int f = 0; f < 9; ++f) {
    float2 e = ((const float2*)(aemb + (size_t)(f * 128 + xr[f]) * 128))[lane];
    sx += e.x; sy += e.y;
  }
  ((float2*)raw)[idx] = make_float2(sx, sy);
}

// One wave per node; applies previous layer's BN2(+relu) on the fly to fp32
// raw. zin(bf16) = (1+eps)*hbn + sum_e relu(hbn[src] + comb[c]).
// Edge loop unrolled x8: all 17 loads issued before first use (MLP ~8).
// Block 0 zeroes stats[0..511] (BN1 accums).
__global__ __launch_bounds__(256) void aggregate_k(
    const float* __restrict__ raw, const ushort_t* __restrict__ comb,
    const uint32_t* __restrict__ sorted, const int* __restrict__ rs,
    const float* __restrict__ eps, int layer, ushort_t* __restrict__ zin,
    float* __restrict__ stats, const float* __restrict__ stats2,
    const float* __restrict__ g, const float* __restrict__ bb,
    float invN, int N)
{
  if (blockIdx.x == 0) {
    stats[threadIdx.x] = 0.f;
    stats[threadIdx.x + 256] = 0.f;
  }
  int wave = threadIdx.x >> 6, lane = threadIdx.x & 63;
  int n = blockIdx.x * 4 + wave;
  if (n >= N) return;
  float scx = 1.f, scy = 1.f, shx = 0.f, shy = 0.f;
  const bool bn = (stats2 != nullptr);
  if (bn) {
    int c0 = 2 * lane, c1 = c0 + 1;
    float mu0 = stats2[c0] * invN, mu1 = stats2[c1] * invN;
    float v0 = stats2[128 + c0] * invN - mu0 * mu0;
    float v1 = stats2[128 + c1] * invN - mu1 * mu1;
    scx = rsqrtf(v0 + 1e-5f) * g[c0];
    scy = rsqrtf(v1 + 1e-5f) * g[c1];
    shx = bb[c0] - mu0 * scx;
    shy = bb[c1] - mu1 * scy;
  }
  int beg = rs[n], end = rs[n + 1];
  const float2* h2 = (const float2*)raw;
  const uint_t* cb = ((const uint_t*)comb) + (size_t)layer * 4096 * 64;
  float ax = 0.f, ay = 0.f;
  int i = beg;
  for (; i + 8 <= end; i += 8) {
    uint32_t p[8];
#pragma unroll
    for (int j = 0; j < 8; ++j) p[j] = sorted[i + j];
    float2 hv[8];
    uint_t ee[8];
#pragma unroll
    for (int j = 0; j < 8; ++j) {
      hv[j] = h2[(size_t)(p[j] & 0xFFFFu) * 64 + lane];
      ee[j] = cb[(p[j] >> 16) * 64 + lane];
    }
#pragma unroll
    for (int j = 0; j < 8; ++j) {
      float hx = hv[j].x, hy = hv[j].y;
      if (bn) {
        hx = fmaxf(fmaf(hx, scx, shx), 0.f);
        hy = fmaxf(fmaf(hy, scy, shy), 0.f);
      }
      ax += fmaxf(hx + bf2f(ee[j]), 0.f);
      ay += fmaxf(hy + bf2f(ee[j] >> 16), 0.f);
    }
  }
  for (; i < end; ++i) {
    uint32_t p = sorted[i];
    uint_t ee = cb[(p >> 16) * 64 + lane];
    float2 hv = h2[(size_t)(p & 0xFFFFu) * 64 + lane];
    if (bn) {
      hv.x = fmaxf(fmaf(hv.x, scx, shx), 0.f);
      hv.y = fmaxf(fmaf(hv.y, scy, shy), 0.f);
    }
    ax += fmaxf(hv.x + bf2f(ee), 0.f);
    ay += fmaxf(hv.y + bf2f(ee >> 16), 0.f);
  }
  float s = 1.f + eps[layer];
  float2 hn = h2[n * 64 + lane];
  if (bn) {
    hn.x = fmaxf(fmaf(hn.x, scx, shx), 0.f);
    hn.y = fmaxf(fmaf(hn.y, scy, shy), 0.f);
  }
  ((uint_t*)zin)[n * 64 + lane] = pack2(fmaf(s, hn.x, ax), fmaf(s, hn.y, ay));
}

// ---------- MFMA GEMMs ----------
// A staged in LDS, XOR-swizzled in 16B chunks: elem (r,k) at col
// ((k>>3)^(r&15))*8 + (k&7).   Frags: A[m=lane&31][k=(lane>>5)*8+j],
// B[k][n=lane&31][k=(lane>>5)*8+j] (pre-swizzled),
// C/D col=lane&31, row=(reg&3)+8*(reg>>2)+4*(lane>>5).

// [64,128]@[128,256]+bias -> fp32 out. Input either bf16 (inbf) or fp32
// (inf, with optional BN via stats2 — final projection). Optional BN1
// stats accum + zeroing of next stats region.
__global__ __launch_bounds__(256) void gemm1_k(
    const ushort_t* __restrict__ inbf, const float* __restrict__ inf,
    const ushort_t* __restrict__ bswz, const float* __restrict__ bias,
    float* __restrict__ outf, float* __restrict__ statsOut,
    float* __restrict__ zeroPtr, int zeroN,
    const float* __restrict__ stats2, const float* __restrict__ g,
    const float* __restrict__ bb, float invN)
{
  __shared__ ushort_t As[64 * 128];
  __shared__ float sc[128], sh[128];
  int tid = threadIdx.x;
  int wave = tid >> 6, lane = tid & 63;
  int lr = lane & 31, half = lane >> 5;
  int row0 = blockIdx.x * 64;
  if (zeroPtr && blockIdx.x == 0 && tid < zeroN) zeroPtr[tid] = 0.f;
  if (stats2 && tid < 128) {
    int c = tid;
    float mu = stats2[c] * invN;
    float var = stats2[128 + c] * invN - mu * mu;
    float r = rsqrtf(var + 1e-5f) * g[c];
    sc[c] = r;
    sh[c] = bb[c] - mu * r;
  }
  __syncthreads();
  if (inbf) {
    const uint2* src = (const uint2*)(inbf + (size_t)row0 * 128);
#pragma unroll
    for (int i = 0; i < 8; ++i) {
      int idx = tid + 256 * i;           // 2048 uint2 = 64x128
      int r = idx >> 5, c = (idx & 31) * 4;
      uint2 v = src[idx];
      int scol = (((c >> 3) ^ (r & 15)) << 3) | (c & 7);
      *(uint2*)&As[r * 128 + scol] = v;
    }
  } else {
    const float4* src = (const float4*)(inf + (size_t)row0 * 128);
#pragma unroll
    for (int i = 0; i < 8; ++i) {
      int idx = tid + 256 * i;           // 2048 float4 = 64x128
      int r = idx >> 5, c = (idx & 31) * 4;
      float4 v = src[idx];
      if (stats2) {
        v.x = fmaf(v.x, sc[c], sh[c]);
        v.y = fmaf(v.y, sc[c + 1], sh[c + 1]);
        v.z = fmaf(v.z, sc[c + 2], sh[c + 2]);
        v.w = fmaf(v.w, sc[c + 3], sh[c + 3]);
      }
      uint2 o;
      o.x = pack2(v.x, v.y);
      o.y = pack2(v.z, v.w);
      int scol = (((c >> 3) ^ (r & 15)) << 3) | (c & 7);
      *(uint2*)&As[r * 128 + scol] = o;
    }
  }
  __syncthreads();
  int nt0 = wave * 2, nt1 = nt0 + 1;
  f32x16 acc00 = zero16(), acc01 = zero16(), acc10 = zero16(), acc11 = zero16();
  const bf16x8* Bp = (const bf16x8*)bswz;
#pragma unroll
  for (int s = 0; s < 8; ++s) {
    int k = s * 16 + half * 8;
    int scol = ((k >> 3) ^ (lr & 15)) << 3;
    bf16x8 a0 = *(const bf16x8*)&As[lr * 128 + scol];
    bf16x8 a1 = *(const bf16x8*)&As[(32 + lr) * 128 + scol];
    bf16x8 b0 = Bp[(s * 8 + nt0) * 64 + lane];
    bf16x8 b1 = Bp[(s * 8 + nt1) * 64 + lane];
    acc00 = MFMA32(a0, b0, acc00);
    acc10 = MFMA32(a1, b0, acc10);
    acc01 = MFMA32(a0, b1, acc01);
    acc11 = MFMA32(a1, b1, acc11);
  }
  int col0 = nt0 * 32 + lr, col1 = nt1 * 32 + lr;
  float bv0 = bias[col0], bv1 = bias[col1];
  float s0 = 0, q0 = 0, s1 = 0, q1 = 0;
  auto emit = [&](const f32x16& a, int mtb, int col, float bv, float& s, float& q) {
#pragma unroll
    for (int r2 = 0; r2 < 16; ++r2) {
      int row = row0 + mtb + (r2 & 3) + 8 * (r2 >> 2) + 4 * half;
      float v = a[r2] + bv;
      outf[(size_t)row * 256 + col] = v;
      s += v;
      q += v * v;
    }
  };
  emit(acc00, 0, col0, bv0, s0, q0);
  emit(acc10, 32, col0, bv0, s0, q0);
  emit(acc01, 0, col1, bv1, s1, q1);
  emit(acc11, 32, col1, bv1, s1, q1);
  if (statsOut) {
    s0 += __shfl_xor(s0, 32);
    q0 += __shfl_xor(q0, 32);
    s1 += __shfl_xor(s1, 32);
    q1 += __shfl_xor(q1, 32);
    if (lane < 32) {
      atomicAdd(&statsOut[col0], s0);
      atomicAdd(&statsOut[256 + col0], q0);
      atomicAdd(&statsOut[col1], s1);
      atomicAdd(&statsOut[256 + col1], q1);
    }
  }
}

// BN1+relu on fp32 load -> bf16 LDS, [64,256]@[256,128]+bias -> raw fp32;
// BN2 stats out.
__global__ __launch_bounds__(256) void gemm2_k(
    const float* __restrict__ in, const ushort_t* __restrict__ bswz,
    const float* __restrict__ bias, const float* __restrict__ stats1,
    const float* __restrict__ g, const float* __restrict__ bb,
    float* __restrict__ outf, float* __restrict__ statsOut, float invN)
{
  __shared__ ushort_t As[64 * 256];
  __shared__ float sc[256], sh[256];
  int tid = threadIdx.x;
  int wave = tid >> 6, lane = tid & 63;
  int lr = lane & 31, half = lane >> 5;
  int row0 = blockIdx.x * 64;
  {
    int c = tid;
    float mu = stats1[c] * invN;
    float var = stats1[256 + c] * invN - mu * mu;
    float r = rsqrtf(var + 1e-5f) * g[c];
    sc[c] = r;
    sh[c] = bb[c] - mu * r;
  }
  __syncthreads();
  {
    const float4* src = (const float4*)(in + (size_t)row0 * 256);
#pragma unroll
    for (int i = 0; i < 16; ++i) {
      int idx = tid + 256 * i;           // 4096 float4 = 64x256
      int r = idx >> 6, c = (idx & 63) * 4;
      float4 v = src[idx];
      float f0 = fmaxf(fmaf(v.x, sc[c], sh[c]), 0.f);
      float f1 = fmaxf(fmaf(v.y, sc[c + 1], sh[c + 1]), 0.f);
      float f2 = fmaxf(fmaf(v.z, sc[c + 2], sh[c + 2]), 0.f);
      float f3 = fmaxf(fmaf(v.w, sc[c + 3], sh[c + 3]), 0.f);
      uint2 o;
      o.x = pack2(f0, f1);
      o.y = pack2(f2, f3);
      int scol = (((c >> 3) ^ (r & 15)) << 3) | (c & 7);
      *(uint2*)&As[r * 256 + scol] = o;
    }
  }
  __syncthreads();
  int nt = wave;
  f32x16 acc0 = zero16(), acc1 = zero16();
  const bf16x8* Bp = (const bf16x8*)bswz;
#pragma unroll
  for (int s = 0; s < 16; ++s) {
    int k = s * 16 + half * 8;
    int scol = ((k >> 3) ^ (lr & 15)) << 3;
    bf16x8 a0 = *(const bf16x8*)&As[lr * 256 + scol];
    bf16x8 a1 = *(const bf16x8*)&As[(32 + lr) * 256 + scol];
    bf16x8 b = Bp[(s * 4 + nt) * 64 + lane];
    acc0 = MFMA32(a0, b, acc0);
    acc1 = MFMA32(a1, b, acc1);
  }
  int col = nt * 32 + lr;
  float bv = bias[col];
  float s0 = 0, q0 = 0;
  auto emit = [&](const f32x16& a, int mtb) {
#pragma unroll
    for (int r2 = 0; r2 < 16; ++r2) {
      int row = row0 + mtb + (r2 & 3) + 8 * (r2 >> 2) + 4 * half;
      float v = a[r2] + bv;
      outf[(size_t)row * 128 + col] = v;
      s0 += v;
      q0 += v * v;
    }
  };
  emit(acc0, 0);
  emit(acc1, 32);
  s0 += __shfl_xor(s0, 32);
  q0 += __shfl_xor(q0, 32);
  if (lane < 32) {
    atomicAdd(&statsOut[col], s0);
    atomicAdd(&statsOut[128 + col], q0);
  }
}

extern "C" void kernel_launch(void* const* d_in, const int* in_sizes, int n_in,
                              void* d_out, int out_size, void* d_ws, size_t ws_size,
                              hipStream_t stream)
{
  const int* x = (const int*)d_in[0];
  const int* ei = (const int*)d_in[1];
  const int* ea = (const int*)d_in[2];
  const float* aemb = (const float*)d_in[3];
  const float* bemb = (const float*)d_in[4];
  const float* eps = (const float*)d_in[5];
  const float* w1 = (const float*)d_in[6];
  const float* b1 = (const float*)d_in[7];
  const float* bn1g = (const float*)d_in[8];
  const float* bn1b = (const float*)d_in[9];
  const float* w2 = (const float*)d_in[10];
  const float* b2 = (const float*)d_in[11];
  const float* bng = (const float*)d_in[12];
  const float* bnb = (const float*)d_in[13];
  const float* linw = (const float*)d_in[14];
  const float* linb = (const float*)d_in[15];
  int N = in_sizes[0] / 9;   // 40000
  int E = in_sizes[1] / 2;   // 640000
  int nb = (N + 255) / 256;

  char* ws = (char*)d_ws;
  size_t off = 0;
  auto alloc = [&](size_t bytes) {
    void* p = ws + off;
    off += (bytes + 255) & ~(size_t)255;
    return p;
  };
  float* raw = (float*)alloc((size_t)N * 128 * 4);         // pre-BN h, fp32
  float* z1  = (float*)alloc((size_t)N * 256 * 4);         // pre-BN1, fp32
  ushort_t* zin = (ushort_t*)alloc((size_t)N * 128 * 2);   // GEMM1 input, bf16
  ushort_t* comb = (ushort_t*)alloc((size_t)5 * 4096 * 128 * 2);
  ushort_t* bswz1 = (ushort_t*)alloc((size_t)6 * 32768 * 2);  // 5x w1 + linw
  ushort_t* bswz2 = (ushort_t*)alloc((size_t)5 * 32768 * 2);
  uint32_t* sorted = (uint32_t*)alloc((size_t)E * 4);
  int* rs = (int*)alloc((size_t)(N + 1) * 4);
  int* cursor = (int*)alloc((size_t)N * 4);
  int* cnt = (int*)alloc((size_t)N * 4);
  int* bsum = (int*)alloc((size_t)nb * 4);
  float* stats = (float*)alloc(768 * 4);
  float invN = 1.f / (float)N;

  bond_comb_k<<<(5 * 4096 * 64 + 255) / 256, 256, 0, stream>>>(bemb, comb);
  for (int l = 0; l < 5; ++l)
    swz_w1_k<<<16, 256, 0, stream>>>(w1 + (size_t)l * 32768, bswz1 + (size_t)l * 32768);
  swz_w1_k<<<16, 256, 0, stream>>>(linw, bswz1 + (size_t)5 * 32768);
  for (int l = 0; l < 5; ++l)
    swz_w2_k<<<16, 256, 0, stream>>>(w2 + (size_t)l * 32768, bswz2 + (size_t)l * 32768);

  atom_encode_k<<<(N * 64 + 255) / 256, 256, 0, stream>>>(x, aemb, raw, N);
  zero_int_k<<<(N + 255) / 256, 256, 0, stream>>>(cnt, N);
  hist_k<<<(E + 255) / 256, 256, 0, stream>>>(ei, cnt, E);
  block_sum_k<<<nb, 256, 0, stream>>>(cnt, bsum, N);
  scan_bsum_k<<<1, 256, 0, stream>>>(bsum, rs + N, nb);
  scan_write_k<<<nb, 256, 0, stream>>>(cnt, bsum, rs, cursor, N);
  scatter_k<<<(E + 255) / 256, 256, 0, stream>>>(ei, ea, cursor, sorted, E);

  for (int l = 0; l < 5; ++l) {
    const float* st2 = (l == 0) ? nullptr : stats + 512;
    const float* gg  = (l == 0) ? nullptr : bng + (size_t)(l - 1) * 128;
    const float* bbb = (l == 0) ? nullptr : bnb + (size_t)(l - 1) * 128;
    aggregate_k<<<(N + 3) / 4, 256, 0, stream>>>(
        raw, comb, sorted, rs, eps, l, zin, stats, st2, gg, bbb, invN, N);
    gemm1_k<<<N / 64, 256, 0, stream>>>(
        zin, nullptr, bswz1 + (size_t)l * 32768, b1 + (size_t)l * 256, z1,
        stats, stats + 512, 256, nullptr, nullptr, nullptr, invN);
    gemm2_k<<<N / 64, 256, 0, stream>>>(
        z1, bswz2 + (size_t)l * 32768, b2 + (size_t)l * 128,
        stats, bn1g + (size_t)l * 256, bn1b + (size_t)l * 256,
        raw, stats + 512, invN);
  }
  gemm1_k<<<N / 64, 256, 0, stream>>>(
      nullptr, raw, bswz1 + (size_t)5 * 32768, linb, (float*)d_out,
      nullptr, nullptr, 0, stats + 512, bng + (size_t)4 * 128, bnb + (size_t)4 * 128, invN);
}

// Round 6
// 729.186 us; speedup vs baseline: 2.0763x; 1.0295x over previous
//
#include <hip/hip_runtime.h>
#include <stdint.h>

// GIN GNN: N=40000, E=640000, H=128, 5 layers, PROJ=256.
// R6: z1 buffer eliminated via recompute trick — gemm1_stats_k emits only
// BN1 column stats; fused_mlp_k recomputes GEMM1 (MFMA idle anyway),
// applies BN1+relu in-register, LDS C->A relayout, GEMM2 + stats2 in one
// kernel. Saves 82MB/layer z1 traffic; arithmetic bit-identical to R5.

typedef unsigned short ushort_t;
typedef unsigned int uint_t;
typedef __attribute__((ext_vector_type(8))) short bf16x8;
typedef __attribute__((ext_vector_type(16))) float f32x16;

#define MFMA32(a, b, c) __builtin_amdgcn_mfma_f32_32x32x16_bf16(a, b, c, 0, 0, 0)

__device__ inline ushort_t f2bf(float f) {
  uint_t u = __builtin_bit_cast(uint_t, f);
  u += 0x7FFFu + ((u >> 16) & 1u);
  return (ushort_t)(u >> 16);
}
__device__ inline float bf2f(uint_t h) {  // low 16 bits
  uint_t u = (h & 0xFFFFu) << 16;
  return __builtin_bit_cast(float, u);
}
__device__ inline uint_t pack2(float a, float b) {
  return (uint_t)f2bf(a) | ((uint_t)f2bf(b) << 16);
}
__device__ inline f32x16 zero16() {
  f32x16 z;
#pragma unroll
  for (int i = 0; i < 16; ++i) z[i] = 0.f;
  return z;
}

// ---------- precompute ----------

// comb[l][c][128] bf16, c = a0|a1<<4|a2<<8
__global__ __launch_bounds__(256) void bond_comb_k(
    const float* __restrict__ bemb, ushort_t* __restrict__ comb)
{
  int idx = blockIdx.x * 256 + threadIdx.x;  // over 5*4096*64
  if (idx >= 5 * 4096 * 64) return;
  int lane = idx & 63, c = (idx >> 6) & 4095, l = idx >> 18;
  const float2* b2 = (const float2*)(bemb + (size_t)l * 3 * 16 * 128);
  float2 e0 = b2[(c & 15) * 64 + lane];
  float2 e1 = b2[(16 + ((c >> 4) & 15)) * 64 + lane];
  float2 e2 = b2[(32 + (c >> 8)) * 64 + lane];
  ((uint_t*)comb)[idx] = pack2(e0.x + e1.x + e2.x, e0.y + e1.y + e2.y);
}

// Swizzle [K=128][N=256] fp32 weight into B-frag order:
// o[((s*8+nt)*64+lane)*8 + j] = bf16(w[(s*16+(lane>>5)*8+j)*256 + nt*32+(lane&31)])
__global__ __launch_bounds__(256) void swz_w1_k(
    const float* __restrict__ w, ushort_t* __restrict__ o)
{
  int t = blockIdx.x * 256 + threadIdx.x;  // 8*8*64 = 4096
  if (t >= 4096) return;
  int lane = t & 63, nt = (t >> 6) & 7, s = t >> 9;
  int kb = s * 16 + (lane >> 5) * 8, n = nt * 32 + (lane & 31);
  ushort_t tmp[8];
#pragma unroll
  for (int j = 0; j < 8; ++j) tmp[j] = f2bf(w[(size_t)(kb + j) * 256 + n]);
  ((uint4*)o)[t] = *(uint4*)tmp;
}

// Swizzle [K=256][N=128]: o[((s*4+nt)*64+lane)*8 + j], s in [0,16), nt in [0,4)
__global__ __launch_bounds__(256) void swz_w2_k(
    const float* __restrict__ w, ushort_t* __restrict__ o)
{
  int t = blockIdx.x * 256 + threadIdx.x;  // 16*4*64 = 4096
  if (t >= 4096) return;
  int lane = t & 63, nt = (t >> 6) & 3, s = t >> 8;
  int kb = s * 16 + (lane >> 5) * 8, n = nt * 32 + (lane & 31);
  ushort_t tmp[8];
#pragma unroll
  for (int j = 0; j < 8; ++j) tmp[j] = f2bf(w[(size_t)(kb + j) * 128 + n]);
  ((uint4*)o)[t] = *(uint4*)tmp;
}

// ---------- graph preprocessing ----------

__global__ void zero_int_k(int* p, int n) {
  int i = blockIdx.x * 256 + threadIdx.x;
  if (i < n) p[i] = 0;
}

__global__ void hist_k(const int* __restrict__ ei, int* __restrict__ cnt, int E) {
  int e = blockIdx.x * 256 + threadIdx.x;
  if (e >= E) return;
  atomicAdd(&cnt[ei[E + e]], 1);
}

__global__ __launch_bounds__(256) void block_sum_k(
    const int* __restrict__ cnt, int* __restrict__ bsum, int N)
{
  __shared__ int red[256];
  int t = threadIdx.x, idx = blockIdx.x * 256 + t;
  red[t] = (idx < N) ? cnt[idx] : 0;
  __syncthreads();
  for (int o = 128; o > 0; o >>= 1) {
    if (t < o) red[t] += red[t + o];
    __syncthreads();
  }
  if (t == 0) bsum[blockIdx.x] = red[0];
}

__global__ __launch_bounds__(256) void scan_bsum_k(
    int* __restrict__ bsum, int* __restrict__ rsN, int nb)
{
  __shared__ int s[256];
  int t = threadIdx.x;
  s[t] = (t < nb) ? bsum[t] : 0;
  __syncthreads();
  for (int o = 1; o < 256; o <<= 1) {
    int v = (t >= o) ? s[t - o] : 0;
    __syncthreads();
    s[t] += v;
    __syncthreads();
  }
  if (t < nb) bsum[t] = (t == 0) ? 0 : s[t - 1];
  if (t == nb - 1) *rsN = s[t];
}

__global__ __launch_bounds__(256) void scan_write_k(
    const int* __restrict__ cnt, const int* __restrict__ bsum,
    int* __restrict__ rs, int* __restrict__ cursor, int N)
{
  __shared__ int s[256];
  int t = threadIdx.x, idx = blockIdx.x * 256 + t;
  int v = (idx < N) ? cnt[idx] : 0;
  s[t] = v;
  __syncthreads();
  for (int o = 1; o < 256; o <<= 1) {
    int u = (t >= o) ? s[t - o] : 0;
    __syncthreads();
    s[t] += u;
    __syncthreads();
  }
  int excl = s[t] - v + bsum[blockIdx.x];
  if (idx < N) { rs[idx] = excl; cursor[idx] = excl; }
}

__global__ void scatter_k(const int* __restrict__ ei, const int* __restrict__ ea,
                          int* __restrict__ cursor, uint32_t* __restrict__ sorted, int E)
{
  int e = blockIdx.x * 256 + threadIdx.x;
  if (e >= E) return;
  int src = ei[e], dst = ei[E + e];
  int a0 = ea[e * 3], a1 = ea[e * 3 + 1], a2 = ea[e * 3 + 2];
  int pos = atomicAdd(&cursor[dst], 1);
  sorted[pos] = (uint32_t)src | ((uint32_t)a0 << 16) | ((uint32_t)a1 << 20) | ((uint32_t)a2 << 24);
}

// ---------- node pipeline ----------

__global__ __launch_bounds__(256) void atom_encode_k(
    const int* __restrict__ x, const float* __restrict__ aemb,
    float* __restrict__ raw, int N)
{
  int idx = blockIdx.x * 256 + threadIdx.x;
  if (idx >= N * 64) return;
  int n = idx >> 6, lane = idx & 63;
  const int* xr = x + n * 9;
  float sx = 0.f, sy = 0.f;
#pragma unroll
  for (int f = 0; f < 9; ++f) {
    float2 e = ((const float2*)(aemb + (size_t)(f * 128 + xr[f]) * 128))[lane];
    sx += e.x; sy += e.y;
  }
  ((float2*)raw)[idx] = make_float2(sx, sy);
}

// One wave per node; applies previous layer's BN2(+relu) on the fly to fp32
// raw. zin(bf16) = (1+eps)*hbn + sum_e relu(hbn[src] + comb[c]).
// Edge loop unrolled x8 (MLP ~8). Block 0 zeroes stats[0..511] (BN1 accums).
__global__ __launch_bounds__(256) void aggregate_k(
    const float* __restrict__ raw, const ushort_t* __restrict__ comb,
    const uint32_t* __restrict__ sorted, const int* __restrict__ rs,
    const float* __restrict__ eps, int layer, ushort_t* __restrict__ zin,
    float* __restrict__ stats, const float* __restrict__ stats2,
    const float* __restrict__ g, const float* __restrict__ bb,
    float invN, int N)
{
  if (blockIdx.x == 0) {
    stats[threadIdx.x] = 0.f;
    stats[threadIdx.x + 256] = 0.f;
  }
  int wave = threadIdx.x >> 6, lane = threadIdx.x & 63;
  int n = blockIdx.x * 4 + wave;
  if (n >= N) return;
  float scx = 1.f, scy = 1.f, shx = 0.f, shy = 0.f;
  const bool bn = (stats2 != nullptr);
  if (bn) {
    int c0 = 2 * lane, c1 = c0 + 1;
    float mu0 = stats2[c0] * invN, mu1 = stats2[c1] * invN;
    float v0 = stats2[128 + c0] * invN - mu0 * mu0;
    float v1 = stats2[128 + c1] * invN - mu1 * mu1;
    scx = rsqrtf(v0 + 1e-5f) * g[c0];
    scy = rsqrtf(v1 + 1e-5f) * g[c1];
    shx = bb[c0] - mu0 * scx;
    shy = bb[c1] - mu1 * scy;
  }
  int beg = rs[n], end = rs[n + 1];
  const float2* h2 = (const float2*)raw;
  const uint_t* cb = ((const uint_t*)comb) + (size_t)layer * 4096 * 64;
  float ax = 0.f, ay = 0.f;
  int i = beg;
  for (; i + 8 <= end; i += 8) {
    uint32_t p[8];
#pragma unroll
    for (int j = 0; j < 8; ++j) p[j] = sorted[i + j];
    float2 hv[8];
    uint_t ee[8];
#pragma unroll
    for (int j = 0; j < 8; ++j) {
      hv[j] = h2[(size_t)(p[j] & 0xFFFFu) * 64 + lane];
      ee[j] = cb[(p[j] >> 16) * 64 + lane];
    }
#pragma unroll
    for (int j = 0; j < 8; ++j) {
      float hx = hv[j].x, hy = hv[j].y;
      if (bn) {
        hx = fmaxf(fmaf(hx, scx, shx), 0.f);
        hy = fmaxf(fmaf(hy, scy, shy), 0.f);
      }
      ax += fmaxf(hx + bf2f(ee[j]), 0.f);
      ay += fmaxf(hy + bf2f(ee[j] >> 16), 0.f);
    }
  }
  for (; i < end; ++i) {
    uint32_t p = sorted[i];
    uint_t ee = cb[(p >> 16) * 64 + lane];
    float2 hv = h2[(size_t)(p & 0xFFFFu) * 64 + lane];
    if (bn) {
      hv.x = fmaxf(fmaf(hv.x, scx, shx), 0.f);
      hv.y = fmaxf(fmaf(hv.y, scy, shy), 0.f);
    }
    ax += fmaxf(hv.x + bf2f(ee), 0.f);
    ay += fmaxf(hv.y + bf2f(ee >> 16), 0.f);
  }
  float s = 1.f + eps[layer];
  float2 hn = h2[n * 64 + lane];
  if (bn) {
    hn.x = fmaxf(fmaf(hn.x, scx, shx), 0.f);
    hn.y = fmaxf(fmaf(hn.y, scy, shy), 0.f);
  }
  ((uint_t*)zin)[n * 64 + lane] = pack2(fmaf(s, hn.x, ax), fmaf(s, hn.y, ay));
}

// ---------- MFMA GEMMs ----------
// A staged in LDS, XOR-swizzled in 16B chunks: elem (r,k) at col
// ((k>>3)^(r&15))*8 + (k&7).   Frags: A[m=lane&31][k=(lane>>5)*8+j],
// B[k][n=lane&31][k=(lane>>5)*8+j] (pre-swizzled),
// C/D col=lane&31, row=(reg&3)+8*(reg>>2)+4*(lane>>5).

// Kernel A: GEMM1 [64,128]@[128,256]+b1, emits ONLY column sum/sumsq into
// statsOut (BN1 accums). Block 0 zeroes stats2 region (256 floats).
__global__ __launch_bounds__(256) void gemm1_stats_k(
    const ushort_t* __restrict__ in, const ushort_t* __restrict__ bswz,
    const float* __restrict__ bias, float* __restrict__ statsOut,
    float* __restrict__ zeroPtr)
{
  __shared__ ushort_t As[64 * 128];
  int tid = threadIdx.x;
  int wave = tid >> 6, lane = tid & 63;
  int lr = lane & 31, half = lane >> 5;
  int row0 = blockIdx.x * 64;
  if (blockIdx.x == 0) zeroPtr[tid] = 0.f;
  {
    const uint2* src = (const uint2*)(in + (size_t)row0 * 128);
#pragma unroll
    for (int i = 0; i < 8; ++i) {
      int idx = tid + 256 * i;
      int r = idx >> 5, c = (idx & 31) * 4;
      uint2 v = src[idx];
      int scol = (((c >> 3) ^ (r & 15)) << 3) | (c & 7);
      *(uint2*)&As[r * 128 + scol] = v;
    }
  }
  __syncthreads();
  int nt0 = wave * 2, nt1 = nt0 + 1;
  f32x16 acc00 = zero16(), acc01 = zero16(), acc10 = zero16(), acc11 = zero16();
  const bf16x8* Bp = (const bf16x8*)bswz;
#pragma unroll
  for (int s = 0; s < 8; ++s) {
    int k = s * 16 + half * 8;
    int scol = ((k >> 3) ^ (lr & 15)) << 3;
    bf16x8 a0 = *(const bf16x8*)&As[lr * 128 + scol];
    bf16x8 a1 = *(const bf16x8*)&As[(32 + lr) * 128 + scol];
    bf16x8 b0 = Bp[(s * 8 + nt0) * 64 + lane];
    bf16x8 b1 = Bp[(s * 8 + nt1) * 64 + lane];
    acc00 = MFMA32(a0, b0, acc00);
    acc10 = MFMA32(a1, b0, acc10);
    acc01 = MFMA32(a0, b1, acc01);
    acc11 = MFMA32(a1, b1, acc11);
  }
  int col0 = nt0 * 32 + lr, col1 = nt1 * 32 + lr;
  float bv0 = bias[col0], bv1 = bias[col1];
  float s0 = 0, q0 = 0, s1 = 0, q1 = 0;
#pragma unroll
  for (int r2 = 0; r2 < 16; ++r2) {
    float v00 = acc00[r2] + bv0, v10 = acc10[r2] + bv0;
    float v01 = acc01[r2] + bv1, v11 = acc11[r2] + bv1;
    s0 += v00 + v10; q0 += v00 * v00 + v10 * v10;
    s1 += v01 + v11; q1 += v01 * v01 + v11 * v11;
  }
  s0 += __shfl_xor(s0, 32); q0 += __shfl_xor(q0, 32);
  s1 += __shfl_xor(s1, 32); q1 += __shfl_xor(q1, 32);
  if (lane < 32) {
    atomicAdd(&statsOut[col0], s0);
    atomicAdd(&statsOut[256 + col0], q0);
    atomicAdd(&statsOut[col1], s1);
    atomicAdd(&statsOut[256 + col1], q1);
  }
}

// Kernel B: recompute GEMM1, BN1+relu in-register (b1 folded into shift),
// C->A relayout via LDS (bf16), GEMM2 [64,256]@[256,128]+b2 -> raw fp32,
// accumulate BN2 stats.
__global__ __launch_bounds__(256) void fused_mlp_k(
    const ushort_t* __restrict__ in, const ushort_t* __restrict__ bswz1,
    const float* __restrict__ b1, const float* __restrict__ stats1,
    const float* __restrict__ g1, const float* __restrict__ bb1,
    const ushort_t* __restrict__ bswz2, const float* __restrict__ b2,
    float* __restrict__ outf, float* __restrict__ stats2, float invN)
{
  __shared__ ushort_t As[64 * 128];   // zin staging (16 KB)
  __shared__ ushort_t Bs[64 * 256];   // post-BN1 z1 tile (32 KB)
  __shared__ float sc1[256], sh1[256];
  int tid = threadIdx.x;
  int wave = tid >> 6, lane = tid & 63;
  int lr = lane & 31, half = lane >> 5;
  int row0 = blockIdx.x * 64;
  {
    int c = tid;
    float mu = stats1[c] * invN;
    float var = stats1[256 + c] * invN - mu * mu;
    float r = rsqrtf(var + 1e-5f) * g1[c];
    sc1[c] = r;
    sh1[c] = bb1[c] - mu * r + b1[c] * r;   // fold bias1 into shift
  }
  {
    const uint2* src = (const uint2*)(in + (size_t)row0 * 128);
#pragma unroll
    for (int i = 0; i < 8; ++i) {
      int idx = tid + 256 * i;
      int r = idx >> 5, c = (idx & 31) * 4;
      uint2 v = src[idx];
      int scol = (((c >> 3) ^ (r & 15)) << 3) | (c & 7);
      *(uint2*)&As[r * 128 + scol] = v;
    }
  }
  __syncthreads();
  int nt0 = wave * 2, nt1 = nt0 + 1;
  f32x16 acc00 = zero16(), acc01 = zero16(), acc10 = zero16(), acc11 = zero16();
  {
    const bf16x8* Bp = (const bf16x8*)bswz1;
#pragma unroll
    for (int s = 0; s < 8; ++s) {
      int k = s * 16 + half * 8;
      int scol = ((k >> 3) ^ (lr & 15)) << 3;
      bf16x8 a0 = *(const bf16x8*)&As[lr * 128 + scol];
      bf16x8 a1 = *(const bf16x8*)&As[(32 + lr) * 128 + scol];
      bf16x8 b0v = Bp[(s * 8 + nt0) * 64 + lane];
      bf16x8 b1v = Bp[(s * 8 + nt1) * 64 + lane];
      acc00 = MFMA32(a0, b0v, acc00);
      acc10 = MFMA32(a1, b0v, acc10);
      acc01 = MFMA32(a0, b1v, acc01);
      acc11 = MFMA32(a1, b1v, acc11);
    }
  }
  {
    int col0 = nt0 * 32 + lr, col1 = nt1 * 32 + lr;
    float sc0v = sc1[col0], sh0v = sh1[col0];
    float sc1v = sc1[col1], sh1v = sh1[col1];
    auto wr = [&](const f32x16& a, int mtb, int col, float scv, float shv) {
#pragma unroll
      for (int r2 = 0; r2 < 16; ++r2) {
        int row = mtb + (r2 & 3) + 8 * (r2 >> 2) + 4 * half;
        float v = fmaxf(fmaf(a[r2], scv, shv), 0.f);
        int scol = (((col >> 3) ^ (row & 15)) << 3) | (col & 7);
        Bs[row * 256 + scol] = f2bf(v);
      }
    };
    wr(acc00, 0, col0, sc0v, sh0v);
    wr(acc10, 32, col0, sc0v, sh0v);
    wr(acc01, 0, col1, sc1v, sh1v);
    wr(acc11, 32, col1, sc1v, sh1v);
  }
  __syncthreads();
  f32x16 acc0 = zero16(), acc1 = zero16();
  {
    const bf16x8* Bp2 = (const bf16x8*)bswz2;
#pragma unroll
    for (int s = 0; s < 16; ++s) {
      int k = s * 16 + half * 8;
      int scol = ((k >> 3) ^ (lr & 15)) << 3;
      bf16x8 a0 = *(const bf16x8*)&Bs[lr * 256 + scol];
      bf16x8 a1 = *(const bf16x8*)&Bs[(32 + lr) * 256 + scol];
      bf16x8 b = Bp2[(s * 4 + wave) * 64 + lane];
      acc0 = MFMA32(a0, b, acc0);
      acc1 = MFMA32(a1, b, acc1);
    }
  }
  int col = wave * 32 + lr;
  float bv = b2[col];
  float s0 = 0, q0 = 0;
  auto emit = [&](const f32x16& a, int mtb) {
#pragma unroll
    for (int r2 = 0; r2 < 16; ++r2) {
      int row = row0 + mtb + (r2 & 3) + 8 * (r2 >> 2) + 4 * half;
      float v = a[r2] + bv;
      outf[(size_t)row * 128 + col] = v;
      s0 += v;
      q0 += v * v;
    }
  };
  emit(acc0, 0);
  emit(acc1, 32);
  s0 += __shfl_xor(s0, 32);
  q0 += __shfl_xor(q0, 32);
  if (lane < 32) {
    atomicAdd(&stats2[col], s0);
    atomicAdd(&stats2[128 + col], q0);
  }
}

// Final projection: BN(stats2) on fp32 raw at load (no relu), then
// [64,128]@[128,256]+linb -> fp32 out.
__global__ __launch_bounds__(256) void final_proj_k(
    const float* __restrict__ inf, const ushort_t* __restrict__ bswz,
    const float* __restrict__ bias, const float* __restrict__ stats2,
    const float* __restrict__ g, const float* __restrict__ bb,
    float* __restrict__ outf, float invN)
{
  __shared__ ushort_t As[64 * 128];
  __shared__ float sc[128], sh[128];
  int tid = threadIdx.x;
  int wave = tid >> 6, lane = tid & 63;
  int lr = lane & 31, half = lane >> 5;
  int row0 = blockIdx.x * 64;
  if (tid < 128) {
    int c = tid;
    float mu = stats2[c] * invN;
    float var = stats2[128 + c] * invN - mu * mu;
    float r = rsqrtf(var + 1e-5f) * g[c];
    sc[c] = r;
    sh[c] = bb[c] - mu * r;
  }
  __syncthreads();
  {
    const float4* src = (const float4*)(inf + (size_t)row0 * 128);
#pragma unroll
    for (int i = 0; i < 8; ++i) {
      int idx = tid + 256 * i;
      int r = idx >> 5, c = (idx & 31) * 4;
      float4 v = src[idx];
      v.x = fmaf(v.x, sc[c], sh[c]);
      v.y = fmaf(v.y, sc[c + 1], sh[c + 1]);
      v.z = fmaf(v.z, sc[c + 2], sh[c + 2]);
      v.w = fmaf(v.w, sc[c + 3], sh[c + 3]);
      uint2 o;
      o.x = pack2(v.x, v.y);
      o.y = pack2(v.z, v.w);
      int scol = (((c >> 3) ^ (r & 15)) << 3) | (c & 7);
      *(uint2*)&As[r * 128 + scol] = o;
    }
  }
  __syncthreads();
  int nt0 = wave * 2, nt1 = nt0 + 1;
  f32x16 acc00 = zero16(), acc01 = zero16(), acc10 = zero16(), acc11 = zero16();
  const bf16x8* Bp = (const bf16x8*)bswz;
#pragma unroll
  for (int s = 0; s < 8; ++s) {
    int k = s * 16 + half * 8;
    int scol = ((k >> 3) ^ (lr & 15)) << 3;
    bf16x8 a0 = *(const bf16x8*)&As[lr * 128 + scol];
    bf16x8 a1 = *(const bf16x8*)&As[(32 + lr) * 128 + scol];
    bf16x8 b0 = Bp[(s * 8 + nt0) * 64 + lane];
    bf16x8 b1 = Bp[(s * 8 + nt1) * 64 + lane];
    acc00 = MFMA32(a0, b0, acc00);
    acc10 = MFMA32(a1, b0, acc10);
    acc01 = MFMA32(a0, b1, acc01);
    acc11 = MFMA32(a1, b1, acc11);
  }
  int col0 = nt0 * 32 + lr, col1 = nt1 * 32 + lr;
  float bv0 = bias[col0], bv1 = bias[col1];
  auto emit = [&](const f32x16& a, int mtb, int col, float bv) {
#pragma unroll
    for (int r2 = 0; r2 < 16; ++r2) {
      int row = row0 + mtb + (r2 & 3) + 8 * (r2 >> 2) + 4 * half;
      outf[(size_t)row * 256 + col] = a[r2] + bv;
    }
  };
  emit(acc00, 0, col0, bv0);
  emit(acc10, 32, col0, bv0);
  emit(acc01, 0, col1, bv1);
  emit(acc11, 32, col1, bv1);
}

extern "C" void kernel_launch(void* const* d_in, const int* in_sizes, int n_in,
                              void* d_out, int out_size, void* d_ws, size_t ws_size,
                              hipStream_t stream)
{
  const int* x = (const int*)d_in[0];
  const int* ei = (const int*)d_in[1];
  const int* ea = (const int*)d_in[2];
  const float* aemb = (const float*)d_in[3];
  const float* bemb = (const float*)d_in[4];
  const float* eps = (const float*)d_in[5];
  const float* w1 = (const float*)d_in[6];
  const float* b1 = (const float*)d_in[7];
  const float* bn1g = (const float*)d_in[8];
  const float* bn1b = (const float*)d_in[9];
  const float* w2 = (const float*)d_in[10];
  const float* b2 = (const float*)d_in[11];
  const float* bng = (const float*)d_in[12];
  const float* bnb = (const float*)d_in[13];
  const float* linw = (const float*)d_in[14];
  const float* linb = (const float*)d_in[15];
  int N = in_sizes[0] / 9;   // 40000
  int E = in_sizes[1] / 2;   // 640000
  int nb = (N + 255) / 256;

  char* ws = (char*)d_ws;
  size_t off = 0;
  auto alloc = [&](size_t bytes) {
    void* p = ws + off;
    off += (bytes + 255) & ~(size_t)255;
    return p;
  };
  float* raw = (float*)alloc((size_t)N * 128 * 4);         // pre-BN h, fp32
  ushort_t* zin = (ushort_t*)alloc((size_t)N * 128 * 2);   // GEMM1 input, bf16
  ushort_t* comb = (ushort_t*)alloc((size_t)5 * 4096 * 128 * 2);
  ushort_t* bswz1 = (ushort_t*)alloc((size_t)6 * 32768 * 2);  // 5x w1 + linw
  ushort_t* bswz2 = (ushort_t*)alloc((size_t)5 * 32768 * 2);
  uint32_t* sorted = (uint32_t*)alloc((size_t)E * 4);
  int* rs = (int*)alloc((size_t)(N + 1) * 4);
  int* cursor = (int*)alloc((size_t)N * 4);
  int* cnt = (int*)alloc((size_t)N * 4);
  int* bsum = (int*)alloc((size_t)nb * 4);
  float* stats = (float*)alloc(768 * 4);  // [sum1:256][sq1:256][sum2:128][sq2:128]
  float invN = 1.f / (float)N;

  bond_comb_k<<<(5 * 4096 * 64 + 255) / 256, 256, 0, stream>>>(bemb, comb);
  for (int l = 0; l < 5; ++l)
    swz_w1_k<<<16, 256, 0, stream>>>(w1 + (size_t)l * 32768, bswz1 + (size_t)l * 32768);
  swz_w1_k<<<16, 256, 0, stream>>>(linw, bswz1 + (size_t)5 * 32768);
  for (int l = 0; l < 5; ++l)
    swz_w2_k<<<16, 256, 0, stream>>>(w2 + (size_t)l * 32768, bswz2 + (size_t)l * 32768);

  atom_encode_k<<<(N * 64 + 255) / 256, 256, 0, stream>>>(x, aemb, raw, N);
  zero_int_k<<<(N + 255) / 256, 256, 0, stream>>>(cnt, N);
  hist_k<<<(E + 255) / 256, 256, 0, stream>>>(ei, cnt, E);
  block_sum_k<<<nb, 256, 0, stream>>>(cnt, bsum, N);
  scan_bsum_k<<<1, 256, 0, stream>>>(bsum, rs + N, nb);
  scan_write_k<<<nb, 256, 0, stream>>>(cnt, bsum, rs, cursor, N);
  scatter_k<<<(E + 255) / 256, 256, 0, stream>>>(ei, ea, cursor, sorted, E);

  for (int l = 0; l < 5; ++l) {
    const float* st2 = (l == 0) ? nullptr : stats + 512;
    const float* gg  = (l == 0) ? nullptr : bng + (size_t)(l - 1) * 128;
    const float* bbb = (l == 0) ? nullptr : bnb + (size_t)(l - 1) * 128;
    aggregate_k<<<(N + 3) / 4, 256, 0, stream>>>(
        raw, comb, sorted, rs, eps, l, zin, stats, st2, gg, bbb, invN, N);
    gemm1_stats_k<<<N / 64, 256, 0, stream>>>(
        zin, bswz1 + (size_t)l * 32768, b1 + (size_t)l * 256,
        stats, stats + 512);
    fused_mlp_k<<<N / 64, 256, 0, stream>>>(
        zin, bswz1 + (size_t)l * 32768, b1 + (size_t)l * 256,
        stats, bn1g + (size_t)l * 256, bn1b + (size_t)l * 256,
        bswz2 + (size_t)l * 32768, b2 + (size_t)l * 128,
        raw, stats + 512, invN);
  }
  final_proj_k<<<N / 64, 256, 0, stream>>>(
      raw, bswz1 + (size_t)5 * 32768, linb, stats + 512,
      bng + (size_t)4 * 128, bnb + (size_t)4 * 128, (float*)d_out, invN);
}